// Round 1
// baseline (1000.420 us; speedup 1.0000x reference)
//
#include <hip/hip_runtime.h>
#include <math.h>

#define N_NODES 200000
#define N_EDGES 6400000
#define F_IN    128
#define H_HID   6
#define C_OUT   10
#define G_BATCH 64

#define TILE_E  16384                                // edges per sort tile
#define NT      ((N_EDGES + TILE_E - 1) / TILE_E)    // 391 tiles
#define EPT     (TILE_E / 512)                       // 32 edges per thread
#define BSH     9                                    // bucket = col >> 9
#define BNODES  512                                  // nodes per bucket
#define NBUCK   ((N_NODES + BNODES - 1) / BNODES)    // 391 buckets
#define BCAP    18432                                // slots per bucket (mean 16384, +16 sigma)

// ---- bf16 helpers (RNE) ---------------------------------------------------
__device__ __forceinline__ unsigned short f2bf(float f) {
    unsigned u = __float_as_uint(f);
    u += 0x7fff + ((u >> 16) & 1);
    return (unsigned short)(u >> 16);
}
__device__ __forceinline__ unsigned pack2(float a, float b) {
    return (unsigned)f2bf(a) | ((unsigned)f2bf(b) << 16);
}
__device__ __forceinline__ float bf_lo(unsigned u) { return __uint_as_float(u << 16); }
__device__ __forceinline__ float bf_hi(unsigned u) { return __uint_as_float(u & 0xffff0000u); }

// ---------------------------------------------------------------------------
// A) scatter with on-the-fly reservation: LDS-sort tile by bucket, reserve each
//    bucket's run via ONE global atomic, stream runs into fixed bucket regions.
//    Payload packed: (col&511)<<18 | row.  Also counts per-node in-degree
//    (global no-return atomics, hidden under this latency-bound kernel).
__global__ __launch_bounds__(512) void scatterA_kernel(const int* __restrict__ row,
                                                       const int* __restrict__ col,
                                                       int* __restrict__ gcur,
                                                       int* __restrict__ deg,
                                                       int* __restrict__ binned, int E) {
    __shared__ int sortbuf[TILE_E];   // 64 KB
    __shared__ int cnt[512];
    __shared__ int pos[513];
    __shared__ int cur[512];
    __shared__ int lbase[512];
    int t = blockIdx.x, tid = threadIdx.x;
    int base = t * TILE_E;
    int tile_n = min(TILE_E, E - base);

    cnt[tid] = 0;
    __syncthreads();

    // phase 0: read edges into registers, LDS histogram over buckets + global degree
    int myval[EPT];
#pragma unroll
    for (int k = 0; k < EPT; ++k) {
        int e = base + k * 512 + tid;
        if (e < E) {
            int c = col[e];
            myval[k] = ((c & (BNODES - 1)) << 18) | row[e];
            atomicAdd(&cnt[c >> BSH], 1);
            atomicAdd(&deg[c], 1);
        }
    }
    __syncthreads();

    // phase 1: inclusive scan of cnt (512 wide), then exclusive + cursors
    pos[tid] = cnt[tid];
    __syncthreads();
    for (int off = 1; off < 512; off <<= 1) {
        int tv = (tid >= off) ? pos[tid - off] : 0;
        __syncthreads();
        pos[tid] += tv;
        __syncthreads();
    }
    int incl = pos[tid];
    __syncthreads();
    {
        int excl = incl - cnt[tid];
        pos[tid] = excl;
        cur[tid] = excl;
        if (tid == 511) pos[512] = incl;
        // reserve global space for this tile's run in bucket tid
        if (tid < NBUCK) {
            int c = cnt[tid];
            lbase[tid] = tid * BCAP + (c ? atomicAdd(&gcur[tid], c) : 0);
        }
    }
    __syncthreads();

    // phase 2: place into LDS sort buffer (col re-read is L1/L2-hot)
#pragma unroll
    for (int k = 0; k < EPT; ++k) {
        int e = base + k * 512 + tid;
        if (e < E) {
            int b = col[e] >> BSH;
            int p = atomicAdd(&cur[b], 1);
            sortbuf[p] = myval[k];
        }
    }
    __syncthreads();

    // phase 3: streaming write-out; position -> bucket via LDS binary search
    for (int i = tid; i < tile_n; i += 512) {
        int lo = 0, hi = NBUCK - 1;
        while (lo < hi) {
            int mid = (lo + hi + 1) >> 1;
            if (pos[mid] <= i) lo = mid; else hi = mid - 1;
        }
        binned[lbase[lo] + (i - pos[lo])] = sortbuf[i];
    }
}

// ---------------------------------------------------------------------------
// xw1: h1b row (uint4) = { bf16(d*a0,d*a1), bf16(d*a2,d*a3), bf16(d*a4,d*a5), bits(d) }
// d = rsqrt(deg+1) computed inline (deg counted by scatterA).
__global__ void xw1_kernel(const float* __restrict__ x, const float* __restrict__ W1,
                           const int* __restrict__ deg, uint4* __restrict__ h1b) {
    __shared__ float w[F_IN * H_HID];
    for (int i = threadIdx.x; i < F_IN * H_HID; i += blockDim.x) w[i] = W1[i];
    __syncthreads();
    int n = blockIdx.x * blockDim.x + threadIdx.x;
    if (n >= N_NODES) return;
    float acc[H_HID] = {0.f, 0.f, 0.f, 0.f, 0.f, 0.f};
    const float4* xr = (const float4*)(x + (size_t)n * F_IN);
#pragma unroll 4
    for (int f4 = 0; f4 < F_IN / 4; ++f4) {
        float4 v = xr[f4];
        int f = f4 * 4;
#pragma unroll
        for (int j = 0; j < H_HID; ++j) {
            acc[j] += v.x * w[(f + 0) * H_HID + j] + v.y * w[(f + 1) * H_HID + j]
                    + v.z * w[(f + 2) * H_HID + j] + v.w * w[(f + 3) * H_HID + j];
        }
    }
    float d = rsqrtf((float)deg[n] + 1.0f);
    uint4 o;
    o.x = pack2(d * acc[0], d * acc[1]);
    o.y = pack2(d * acc[2], d * acc[3]);
    o.z = pack2(d * acc[4], d * acc[5]);
    o.w = __float_as_uint(d);
    h1b[n] = o;
}

#define EDGE_ACC(v, l)                                                  \
    atomicAdd(&acc[0][l], bf_lo(v.x)); atomicAdd(&acc[1][l], bf_hi(v.x)); \
    atomicAdd(&acc[2][l], bf_lo(v.y)); atomicAdd(&acc[3][l], bf_hi(v.y)); \
    atomicAdd(&acc[4][l], bf_lo(v.z)); atomicAdd(&acc[5][l], bf_hi(v.z));

// ---------------------------------------------------------------------------
// agg1: one block per bucket. Read bucket's binned run ONCE (coalesced),
// gather h1b[row] (3.2 MB, L2-resident), scatter-add into LDS accumulator
// at local col via ds_add_f32. Then finalize layer 1 (self term, bias, ReLU,
// pre-scale by d) and emit rs. No CSR needed.
__global__ __launch_bounds__(512) void agg1_kernel(const int* __restrict__ gcur,
                                                   const int* __restrict__ binned,
                                                   const uint4* __restrict__ h1b,
                                                   const float* __restrict__ b1,
                                                   uint4* __restrict__ rs) {
    __shared__ float acc[H_HID][BNODES];   // 12 KB; bank = l%32 -> ~2-way on random l
    int b = blockIdx.x, tid = threadIdx.x;
#pragma unroll
    for (int j = 0; j < H_HID; ++j) acc[j][tid] = 0.f;
    __syncthreads();
    int bb = b * BCAP, be = bb + gcur[b];
    int e = bb + tid;
    for (; e + 1536 < be; e += 2048) {      // 4 gathers in flight
        int p0 = binned[e], p1 = binned[e + 512], p2 = binned[e + 1024], p3 = binned[e + 1536];
        uint4 v0 = h1b[p0 & 0x3FFFF], v1 = h1b[p1 & 0x3FFFF],
              v2 = h1b[p2 & 0x3FFFF], v3 = h1b[p3 & 0x3FFFF];
        int l0 = p0 >> 18, l1 = p1 >> 18, l2 = p2 >> 18, l3 = p3 >> 18;
        EDGE_ACC(v0, l0) EDGE_ACC(v1, l1) EDGE_ACC(v2, l2) EDGE_ACC(v3, l3)
    }
    for (; e < be; e += 512) {
        int p = binned[e];
        uint4 v = h1b[p & 0x3FFFF];
        int l = p >> 18;
        EDGE_ACC(v, l)
    }
    __syncthreads();
    int n = b * BNODES + tid;
    if (n < N_NODES) {
        uint4 self = h1b[n];
        float d = __uint_as_float(self.w);
        float sf[H_HID] = {bf_lo(self.x), bf_hi(self.x), bf_lo(self.y),
                           bf_hi(self.y), bf_lo(self.z), bf_hi(self.z)};
        float r[H_HID];
#pragma unroll
        for (int j = 0; j < H_HID; ++j) {
            float vv = d * (acc[j][tid] + sf[j]) + b1[j];
            r[j] = d * (vv > 0.f ? vv : 0.f);    // pre-scaled for layer 2
        }
        uint4 o;
        o.x = pack2(r[0], r[1]);
        o.y = pack2(r[2], r[3]);
        o.z = pack2(r[4], r[5]);
        o.w = self.w;
        rs[n] = o;
    }
}

// ---------------------------------------------------------------------------
// agg2: same edge pass with rs, then W2 post-aggregation + fused pooling.
// Pooling: per-node 10-ch values in LDS, 80 walkers (8 segments x 10 ch) do
// segmented sums over sorted batch with few global atomics.
__global__ __launch_bounds__(512) void agg2_pool_kernel(const int* __restrict__ gcur,
                                                        const int* __restrict__ binned,
                                                        const uint4* __restrict__ rs,
                                                        const float* __restrict__ W2,
                                                        const int* __restrict__ batch,
                                                        float* __restrict__ sums) {
    __shared__ float acc[H_HID][BNODES];     // 12 KB
    __shared__ float w2s[H_HID * C_OUT];
    __shared__ float nv[BNODES][C_OUT + 1];  // pad 11: write stride odd -> conflict-free
    __shared__ int lg[BNODES];
    int b = blockIdx.x, tid = threadIdx.x;
#pragma unroll
    for (int j = 0; j < H_HID; ++j) acc[j][tid] = 0.f;
    if (tid < H_HID * C_OUT) w2s[tid] = W2[tid];
    __syncthreads();
    int bb = b * BCAP, be = bb + gcur[b];
    int e = bb + tid;
    for (; e + 1536 < be; e += 2048) {
        int p0 = binned[e], p1 = binned[e + 512], p2 = binned[e + 1024], p3 = binned[e + 1536];
        uint4 v0 = rs[p0 & 0x3FFFF], v1 = rs[p1 & 0x3FFFF],
              v2 = rs[p2 & 0x3FFFF], v3 = rs[p3 & 0x3FFFF];
        int l0 = p0 >> 18, l1 = p1 >> 18, l2 = p2 >> 18, l3 = p3 >> 18;
        EDGE_ACC(v0, l0) EDGE_ACC(v1, l1) EDGE_ACC(v2, l2) EDGE_ACC(v3, l3)
    }
    for (; e < be; e += 512) {
        int p = binned[e];
        uint4 v = rs[p & 0x3FFFF];
        int l = p >> 18;
        EDGE_ACC(v, l)
    }
    __syncthreads();
    int n = b * BNODES + tid;
    if (n < N_NODES) {
        uint4 self = rs[n];
        float d = __uint_as_float(self.w);
        float t0 = acc[0][tid] + bf_lo(self.x), t1 = acc[1][tid] + bf_hi(self.x),
              t2 = acc[2][tid] + bf_lo(self.y), t3 = acc[3][tid] + bf_hi(self.y),
              t4 = acc[4][tid] + bf_lo(self.z), t5 = acc[5][tid] + bf_hi(self.z);
#pragma unroll
        for (int c = 0; c < C_OUT; ++c) {
            float a2 = t0 * w2s[c]             + t1 * w2s[C_OUT + c]
                     + t2 * w2s[2 * C_OUT + c] + t3 * w2s[3 * C_OUT + c]
                     + t4 * w2s[4 * C_OUT + c] + t5 * w2s[5 * C_OUT + c];
            nv[tid][c] = d * a2;
        }
        lg[tid] = batch[n];
    } else {
#pragma unroll
        for (int c = 0; c < C_OUT; ++c) nv[tid][c] = 0.f;
        lg[tid] = G_BATCH - 1;   // contributes 0.0, any valid graph id works
    }
    __syncthreads();
    // 8 segments x 10 channels; staggered start de-banks segment collisions.
    // Visit order within a segment is irrelevant to segmented sums.
    if (tid < 80) {
        int seg = tid / 10, c = tid - seg * 10;
        int g = -1; float a2 = 0.f;
        for (int ii = 0; ii < 64; ++ii) {
            int w = (seg << 6) + ((ii + 9 * seg) & 63);
            int gw = lg[w];
            if (gw != g) {
                if (g >= 0) atomicAdd(&sums[g * C_OUT + c], a2);
                g = gw; a2 = 0.f;
            }
            a2 += nv[w][c];
        }
        atomicAdd(&sums[g * C_OUT + c], a2);
    }
}

// mean (counts via binary search on sorted batch) + b2 + log_softmax
__global__ void pool_finish_kernel(const float* __restrict__ sums, const int* __restrict__ batch,
                                   const float* __restrict__ b2, float* __restrict__ out) {
    int g = threadIdx.x;
    if (g >= G_BATCH) return;
    int lo = 0, hi = N_NODES;
    while (lo < hi) { int mid = (lo + hi) >> 1; if (batch[mid] < g) lo = mid + 1; else hi = mid; }
    int c0 = lo;
    hi = N_NODES;
    while (lo < hi) { int mid = (lo + hi) >> 1; if (batch[mid] < g + 1) lo = mid + 1; else hi = mid; }
    float inv = 1.0f / fmaxf((float)(lo - c0), 1.0f);
    float v[C_OUT], m = -INFINITY;
#pragma unroll
    for (int c = 0; c < C_OUT; ++c) {
        v[c] = sums[g * C_OUT + c] * inv + b2[c];
        m = fmaxf(m, v[c]);
    }
    float s = 0.f;
#pragma unroll
    for (int c = 0; c < C_OUT; ++c) s += expf(v[c] - m);
    float lse = m + logf(s);
#pragma unroll
    for (int c = 0; c < C_OUT; ++c) out[g * C_OUT + c] = v[c] - lse;
}

extern "C" void kernel_launch(void* const* d_in, const int* in_sizes, int n_in,
                              void* d_out, int out_size, void* d_ws, size_t ws_size,
                              hipStream_t stream) {
    const float* x   = (const float*)d_in[0];
    const int* ei    = (const int*)d_in[1];
    const int* row   = ei;
    const int* col   = ei + N_EDGES;
    const int* batch = (const int*)d_in[2];
    const float* W1  = (const float*)d_in[3];
    const float* b1  = (const float*)d_in[4];
    const float* W2  = (const float*)d_in[5];
    const float* b2  = (const float*)d_in[6];
    float* out = (float*)d_out;

    // workspace layout — region sizes multiples of 16 B so uint4 arrays stay aligned
    char* p = (char*)d_ws;
    float* sums   = (float*)p;  p += (size_t)G_BATCH * C_OUT * 4;       // [zero] 2560B
    int*   gcur   = (int*)p;    p += (size_t)400 * 4;                   // [zero] 1600B (391 used)
    int*   deg    = (int*)p;    p += (size_t)N_NODES * 4;               // [zero] 800000B
    int*   binned = (int*)p;    p += (size_t)NBUCK * BCAP * 4;          // 28.8MB (gapped layout)
    uint4* h1b    = (uint4*)p;  p += (size_t)N_NODES * 16;              // 3.2MB
    uint4* rs     = (uint4*)p;                                          // 3.2MB

    hipMemsetAsync(sums, 0,
                   (size_t)G_BATCH * C_OUT * 4 + 400 * 4 + (size_t)N_NODES * 4, stream);

    scatterA_kernel<<<NT, 512, 0, stream>>>(row, col, gcur, deg, binned, N_EDGES);
    xw1_kernel     <<<(N_NODES + 255) / 256, 256, 0, stream>>>(x, W1, deg, h1b);
    agg1_kernel    <<<NBUCK, 512, 0, stream>>>(gcur, binned, h1b, b1, rs);
    agg2_pool_kernel<<<NBUCK, 512, 0, stream>>>(gcur, binned, rs, W2, batch, sums);
    pool_finish_kernel<<<1, 64, 0, stream>>>(sums, batch, b2, out);
}

// Round 2
// 361.329 us; speedup vs baseline: 2.7687x; 2.7687x over previous
//
#include <hip/hip_runtime.h>
#include <math.h>

#define N_NODES 200000
#define N_EDGES 6400000
#define F_IN    128
#define H_HID   6
#define C_OUT   10
#define G_BATCH 64

#define TILE_E  8192                                 // edges per sort tile (halved: 4 blocks/CU)
#define NT      ((N_EDGES + TILE_E - 1) / TILE_E)    // 782 tiles
#define EPT     (TILE_E / 512)                       // 16 edges per thread
#define BSH     9                                    // bucket = col >> 9
#define BNODES  512                                  // nodes per bucket
#define NBUCK   ((N_NODES + BNODES - 1) / BNODES)    // 391 buckets
#define BCAP    18432                                // slots per bucket (mean 16384, +16 sigma)
#define QCAP    10240                                // passB HALF staging (40 KB; half mean 8192)

// ---- bf16 helpers (RNE) ---------------------------------------------------
__device__ __forceinline__ unsigned short f2bf(float f) {
    unsigned u = __float_as_uint(f);
    u += 0x7fff + ((u >> 16) & 1);
    return (unsigned short)(u >> 16);
}
__device__ __forceinline__ unsigned pack2(float a, float b) {
    return (unsigned)f2bf(a) | ((unsigned)f2bf(b) << 16);
}
__device__ __forceinline__ float bf_lo(unsigned u) { return __uint_as_float(u << 16); }
__device__ __forceinline__ float bf_hi(unsigned u) { return __uint_as_float(u & 0xffff0000u); }

// ---------------------------------------------------------------------------
// A) scatter with on-the-fly reservation: LDS-sort tile by bucket, reserve each
//    bucket's run via ONE global atomic, stream runs into fixed bucket regions.
//    Payload packed: (col&511)<<18 | row.
//    LDS budget: 32KB sortbuf + 2KB cnt/cur (merged) + 2.05KB pos + 2KB lbase
//    = ~38.9 KB -> 4 blocks/CU (32 waves, wave cap).
__global__ __launch_bounds__(512) void scatterA_kernel(const int* __restrict__ row,
                                                       const int* __restrict__ col,
                                                       int* __restrict__ gcur,
                                                       int* __restrict__ binned, int E) {
    __shared__ int sortbuf[TILE_E];   // 32 KB
    __shared__ int cnt[512];          // histogram, then re-used as placement cursor
    __shared__ int pos[513];          // exclusive prefix (bucket -> tile-local start)
    __shared__ int lbase[512];        // bucket -> global run base
    int t = blockIdx.x, tid = threadIdx.x;
    int base = t * TILE_E;
    int tile_n = min(TILE_E, E - base);

    cnt[tid] = 0;
    __syncthreads();

    // phase 0: read edges into registers, LDS histogram over buckets
    int myval[EPT];
#pragma unroll
    for (int k = 0; k < EPT; ++k) {
        int e = base + k * 512 + tid;
        if (e < E) {
            int c = col[e];
            myval[k] = ((c & (BNODES - 1)) << 18) | row[e];
            atomicAdd(&cnt[c >> BSH], 1);
        }
    }
    __syncthreads();

    // phase 1: inclusive scan (512 wide) -> exclusive offsets + cursors + reservation
    pos[tid] = cnt[tid];
    __syncthreads();
    for (int off = 1; off < 512; off <<= 1) {
        int tv = (tid >= off) ? pos[tid - off] : 0;
        __syncthreads();
        pos[tid] += tv;
        __syncthreads();
    }
    int incl = pos[tid];
    __syncthreads();
    {
        int c = cnt[tid];
        int excl = incl - c;
        pos[tid] = excl;
        cnt[tid] = excl;              // becomes the placement cursor
        if (tid == 511) pos[512] = incl;
        if (tid < NBUCK) {            // reserve global space for this tile's run
            lbase[tid] = tid * BCAP + (c ? atomicAdd(&gcur[tid], c) : 0);
        }
    }
    __syncthreads();

    // phase 2: place into LDS sort buffer (col re-read is L1/L2-hot)
#pragma unroll
    for (int k = 0; k < EPT; ++k) {
        int e = base + k * 512 + tid;
        if (e < E) {
            int b = col[e] >> BSH;
            int p = atomicAdd(&cnt[b], 1);
            sortbuf[p] = myval[k];
        }
    }
    __syncthreads();

    // phase 3: streaming write-out; position -> bucket via LDS binary search
    for (int i = tid; i < tile_n; i += 512) {
        int lo = 0, hi = NBUCK - 1;
        while (lo < hi) {
            int mid = (lo + hi + 1) >> 1;
            if (pos[mid] <= i) lo = mid; else hi = mid - 1;
        }
        binned[lbase[lo] + (i - pos[lo])] = sortbuf[i];
    }
}

// B) per-bucket CSR with LDS-staged HALF write-out (coalesced csr).
//    512-node buckets: 391 blocks (fills all 256 CUs), 3 binned sweeps (was 5).
__global__ __launch_bounds__(1024) void passB_kernel(const int* __restrict__ gcur,
                                                     const int* __restrict__ binned,
                                                     int* __restrict__ offs, int* __restrict__ endo,
                                                     float* __restrict__ dis,
                                                     int* __restrict__ csr, int E) {
    __shared__ int cnt[512];
    __shared__ int scn[512];
    __shared__ int cur[256];
    __shared__ int sortbuf[QCAP];     // 40 KB
    int b = blockIdx.x, tid = threadIdx.x;
    int bb = b * BCAP;
    int be = bb + gcur[b];
    if (tid < 512) cnt[tid] = 0;
    __syncthreads();
    // count (unrolled x4 for MLP)
    int e = bb + tid;
    for (; e + 3072 < be; e += 4096) {
        int p0 = binned[e], p1 = binned[e + 1024], p2 = binned[e + 2048], p3 = binned[e + 3072];
        atomicAdd(&cnt[p0 >> 18], 1); atomicAdd(&cnt[p1 >> 18], 1);
        atomicAdd(&cnt[p2 >> 18], 1); atomicAdd(&cnt[p3 >> 18], 1);
    }
    for (; e < be; e += 1024) atomicAdd(&cnt[binned[e] >> 18], 1);
    __syncthreads();
    int v = (tid < 512) ? cnt[tid] : 0;
    if (tid < 512) scn[tid] = v;
    __syncthreads();
    for (int off = 1; off < 512; off <<= 1) {
        int t2 = (tid < 512 && tid >= off) ? scn[tid - off] : 0;
        __syncthreads();
        if (tid < 512) scn[tid] += t2;
        __syncthreads();
    }
    if (tid < 512) {
        int excl = scn[tid] - v;
        scn[tid] = excl;              // own-slot rewrite, no race
        int n = (b << BSH) + tid;
        if (n < N_NODES) {
            offs[n] = bb + excl;
            endo[n] = bb + excl + v;
            dis[n] = rsqrtf((float)v + 1.0f);
        }
    }
    __syncthreads();
    int total = be - bb;
#define PLACE(p) { int loc = (p) >> 18; if ((loc >> 8) == q) {                      \
        int ps = scn[loc] - qbase + atomicAdd(&cur[loc & 255], 1);                  \
        if (ps < QCAP) sortbuf[ps] = (p) & 0x3FFFF;                                 \
        else csr[bb + qbase + ps] = (p) & 0x3FFFF; } }
    for (int q = 0; q < 2; ++q) {
        int qbase = scn[q << 8];
        int qend = (q == 0) ? scn[256] : total;
        int qn = qend - qbase;
        if (tid < 256) cur[tid] = 0;
        __syncthreads();
        int e2 = bb + tid;
        for (; e2 + 3072 < be; e2 += 4096) {
            int p0 = binned[e2], p1 = binned[e2 + 1024], p2 = binned[e2 + 2048], p3 = binned[e2 + 3072];
            PLACE(p0) PLACE(p1) PLACE(p2) PLACE(p3)
        }
        for (; e2 < be; e2 += 1024) { int p = binned[e2]; PLACE(p) }
        __syncthreads();
        int lim = qn < QCAP ? qn : QCAP;
        for (int i = tid; i < lim; i += 1024) csr[bb + qbase + i] = sortbuf[i];
        __syncthreads();
    }
#undef PLACE
}

// ---------------------------------------------------------------------------
// xw1: h1b row (uint4) = { bf16(d*a0,d*a1), bf16(d*a2,d*a3), bf16(d*a4,d*a5), bits(d) }
__global__ void xw1_kernel(const float* __restrict__ x, const float* __restrict__ W1,
                           const float* __restrict__ dis, uint4* __restrict__ h1b) {
    __shared__ float w[F_IN * H_HID];
    for (int i = threadIdx.x; i < F_IN * H_HID; i += blockDim.x) w[i] = W1[i];
    __syncthreads();
    int n = blockIdx.x * blockDim.x + threadIdx.x;
    if (n >= N_NODES) return;
    float acc[H_HID] = {0.f, 0.f, 0.f, 0.f, 0.f, 0.f};
    const float4* xr = (const float4*)(x + (size_t)n * F_IN);
#pragma unroll 4
    for (int f4 = 0; f4 < F_IN / 4; ++f4) {
        float4 v = xr[f4];
        int f = f4 * 4;
#pragma unroll
        for (int j = 0; j < H_HID; ++j) {
            acc[j] += v.x * w[(f + 0) * H_HID + j] + v.y * w[(f + 1) * H_HID + j]
                    + v.z * w[(f + 2) * H_HID + j] + v.w * w[(f + 3) * H_HID + j];
        }
    }
    float d = dis[n];
    uint4 o;
    o.x = pack2(d * acc[0], d * acc[1]);
    o.y = pack2(d * acc[2], d * acc[3]);
    o.z = pack2(d * acc[4], d * acc[5]);
    o.w = __float_as_uint(d);
    h1b[n] = o;
}

// gather conv1: 8 lanes/node, 4-deep unroll (4 gathers in flight per lane).
__global__ void gather1_kernel(const int* __restrict__ offs, const int* __restrict__ endo,
                               const int* __restrict__ csr,
                               const uint4* __restrict__ h1b, const float* __restrict__ b1,
                               uint4* __restrict__ rs) {
    int grp = threadIdx.x >> 3, sub = threadIdx.x & 7;
    int n = blockIdx.x * 32 + grp;
    int s = offs[n], e_end = endo[n];
    float a[H_HID] = {0.f, 0.f, 0.f, 0.f, 0.f, 0.f};
    int e = s + sub;
    for (; e + 24 < e_end; e += 32) {
        int i0 = csr[e], i1 = csr[e + 8], i2 = csr[e + 16], i3 = csr[e + 24];
        uint4 v0 = h1b[i0], v1 = h1b[i1], v2 = h1b[i2], v3 = h1b[i3];
        a[0] += (bf_lo(v0.x) + bf_lo(v1.x)) + (bf_lo(v2.x) + bf_lo(v3.x));
        a[1] += (bf_hi(v0.x) + bf_hi(v1.x)) + (bf_hi(v2.x) + bf_hi(v3.x));
        a[2] += (bf_lo(v0.y) + bf_lo(v1.y)) + (bf_lo(v2.y) + bf_lo(v3.y));
        a[3] += (bf_hi(v0.y) + bf_hi(v1.y)) + (bf_hi(v2.y) + bf_hi(v3.y));
        a[4] += (bf_lo(v0.z) + bf_lo(v1.z)) + (bf_lo(v2.z) + bf_lo(v3.z));
        a[5] += (bf_hi(v0.z) + bf_hi(v1.z)) + (bf_hi(v2.z) + bf_hi(v3.z));
    }
    for (; e < e_end; e += 8) {
        uint4 v = h1b[csr[e]];
        a[0] += bf_lo(v.x); a[1] += bf_hi(v.x);
        a[2] += bf_lo(v.y); a[3] += bf_hi(v.y);
        a[4] += bf_lo(v.z); a[5] += bf_hi(v.z);
    }
#pragma unroll
    for (int j = 0; j < H_HID; ++j)
#pragma unroll
        for (int off = 4; off > 0; off >>= 1) a[j] += __shfl_xor(a[j], off);
    uint4 self = h1b[n];
    float d = __uint_as_float(self.w);
    float sf[H_HID] = {bf_lo(self.x), bf_hi(self.x), bf_lo(self.y),
                       bf_hi(self.y), bf_lo(self.z), bf_hi(self.z)};
    if (sub == 0) {
        float r[H_HID];
#pragma unroll
        for (int j = 0; j < H_HID; ++j) {
            float vv = d * (a[j] + sf[j]) + b1[j];
            r[j] = d * (vv > 0.f ? vv : 0.f);    // pre-scaled for layer 2
        }
        uint4 o;
        o.x = pack2(r[0], r[1]);
        o.y = pack2(r[2], r[3]);
        o.z = pack2(r[4], r[5]);
        o.w = self.w;
        rs[n] = o;
    }
}

// gather conv2 (6ch) + W2 post-aggregation + fused pooling. 8 lanes/node.
__global__ void gather2_pool_kernel(const int* __restrict__ offs, const int* __restrict__ endo,
                                    const int* __restrict__ csr,
                                    const uint4* __restrict__ rs, const float* __restrict__ W2,
                                    const int* __restrict__ batch, float* __restrict__ sums) {
    __shared__ float w2s[H_HID * C_OUT];
    __shared__ float nodeval[32][C_OUT];
    __shared__ int lg[32];
    if (threadIdx.x < H_HID * C_OUT) w2s[threadIdx.x] = W2[threadIdx.x];
    __syncthreads();
    int grp = threadIdx.x >> 3, sub = threadIdx.x & 7;
    int n = blockIdx.x * 32 + grp;
    int s = offs[n], e_end = endo[n];
    float a[H_HID] = {0.f, 0.f, 0.f, 0.f, 0.f, 0.f};
    int e = s + sub;
    for (; e + 24 < e_end; e += 32) {
        int i0 = csr[e], i1 = csr[e + 8], i2 = csr[e + 16], i3 = csr[e + 24];
        uint4 v0 = rs[i0], v1 = rs[i1], v2 = rs[i2], v3 = rs[i3];
        a[0] += (bf_lo(v0.x) + bf_lo(v1.x)) + (bf_lo(v2.x) + bf_lo(v3.x));
        a[1] += (bf_hi(v0.x) + bf_hi(v1.x)) + (bf_hi(v2.x) + bf_hi(v3.x));
        a[2] += (bf_lo(v0.y) + bf_lo(v1.y)) + (bf_lo(v2.y) + bf_lo(v3.y));
        a[3] += (bf_hi(v0.y) + bf_hi(v1.y)) + (bf_hi(v2.y) + bf_hi(v3.y));
        a[4] += (bf_lo(v0.z) + bf_lo(v1.z)) + (bf_lo(v2.z) + bf_lo(v3.z));
        a[5] += (bf_hi(v0.z) + bf_hi(v1.z)) + (bf_hi(v2.z) + bf_hi(v3.z));
    }
    for (; e < e_end; e += 8) {
        uint4 v = rs[csr[e]];
        a[0] += bf_lo(v.x); a[1] += bf_hi(v.x);
        a[2] += bf_lo(v.y); a[3] += bf_hi(v.y);
        a[4] += bf_lo(v.z); a[5] += bf_hi(v.z);
    }
#pragma unroll
    for (int j = 0; j < H_HID; ++j)
#pragma unroll
        for (int off = 4; off > 0; off >>= 1) a[j] += __shfl_xor(a[j], off);
    uint4 self = rs[n];
    float d = __uint_as_float(self.w);
    float t[H_HID] = {a[0] + bf_lo(self.x), a[1] + bf_hi(self.x), a[2] + bf_lo(self.y),
                      a[3] + bf_hi(self.y), a[4] + bf_lo(self.z), a[5] + bf_hi(self.z)};
    {   // all 8 lanes hold the full sum after xor-reduce
        float acc = 0.f;
#pragma unroll
        for (int j = 0; j < H_HID; ++j) acc += t[j] * w2s[j * C_OUT + sub];
        nodeval[grp][sub] = d * acc;
        if (sub < 2) {
            float acc2 = 0.f;
#pragma unroll
            for (int j = 0; j < H_HID; ++j) acc2 += t[j] * w2s[j * C_OUT + sub + 8];
            nodeval[grp][sub + 8] = d * acc2;
        }
    }
    if (sub == 0) lg[grp] = batch[n];
    __syncthreads();
    if (threadIdx.x < C_OUT) {
        int c = threadIdx.x;
        float acc = 0.f;
        int gcur2 = lg[0];
#pragma unroll
        for (int w = 0; w < 32; ++w) {
            if (lg[w] != gcur2) {
                atomicAdd(&sums[gcur2 * C_OUT + c], acc);
                gcur2 = lg[w]; acc = 0.f;
            }
            acc += nodeval[w][c];
        }
        atomicAdd(&sums[gcur2 * C_OUT + c], acc);
    }
}

// mean (counts via binary search on sorted batch) + b2 + log_softmax
__global__ void pool_finish_kernel(const float* __restrict__ sums, const int* __restrict__ batch,
                                   const float* __restrict__ b2, float* __restrict__ out) {
    int g = threadIdx.x;
    if (g >= G_BATCH) return;
    int lo = 0, hi = N_NODES;
    while (lo < hi) { int mid = (lo + hi) >> 1; if (batch[mid] < g) lo = mid + 1; else hi = mid; }
    int c0 = lo;
    hi = N_NODES;
    while (lo < hi) { int mid = (lo + hi) >> 1; if (batch[mid] < g + 1) lo = mid + 1; else hi = mid; }
    float inv = 1.0f / fmaxf((float)(lo - c0), 1.0f);
    float v[C_OUT], m = -INFINITY;
#pragma unroll
    for (int c = 0; c < C_OUT; ++c) {
        v[c] = sums[g * C_OUT + c] * inv + b2[c];
        m = fmaxf(m, v[c]);
    }
    float s = 0.f;
#pragma unroll
    for (int c = 0; c < C_OUT; ++c) s += expf(v[c] - m);
    float lse = m + logf(s);
#pragma unroll
    for (int c = 0; c < C_OUT; ++c) out[g * C_OUT + c] = v[c] - lse;
}

extern "C" void kernel_launch(void* const* d_in, const int* in_sizes, int n_in,
                              void* d_out, int out_size, void* d_ws, size_t ws_size,
                              hipStream_t stream) {
    const float* x   = (const float*)d_in[0];
    const int* ei    = (const int*)d_in[1];
    const int* row   = ei;
    const int* col   = ei + N_EDGES;
    const int* batch = (const int*)d_in[2];
    const float* W1  = (const float*)d_in[3];
    const float* b1  = (const float*)d_in[4];
    const float* W2  = (const float*)d_in[5];
    const float* b2  = (const float*)d_in[6];
    float* out = (float*)d_out;

    // workspace layout — region sizes multiples of 16 B so uint4 arrays stay aligned
    char* p = (char*)d_ws;
    float* sums   = (float*)p;  p += (size_t)G_BATCH * C_OUT * 4;       // [zero] 2560B
    int*   gcur   = (int*)p;    p += (size_t)400 * 4;                   // [zero] 1600B (391 used)
    int*   offs   = (int*)p;    p += (size_t)N_NODES * 4;               // 800000B
    int*   endo   = (int*)p;    p += (size_t)N_NODES * 4;               // 800000B
    float* dis    = (float*)p;  p += (size_t)N_NODES * 4;               // 800000B
    int*   csr    = (int*)p;    p += (size_t)NBUCK * BCAP * 4;          // 28.8MB (gapped layout)
    int*   binned = (int*)p;                                            // 28.8MB, dead after passB
    uint4* h1b    = (uint4*)binned;                                     // 3.2MB, aliases binned
    uint4* rs     = (uint4*)binned + N_NODES;                           // 3.2MB

    hipMemsetAsync(sums, 0, (size_t)G_BATCH * C_OUT * 4 + 400 * 4, stream);   // sums + gcur

    scatterA_kernel<<<NT, 512, 0, stream>>>(row, col, gcur, binned, N_EDGES);
    passB_kernel   <<<NBUCK, 1024, 0, stream>>>(gcur, binned, offs, endo, dis, csr, N_EDGES);
    xw1_kernel     <<<(N_NODES + 255) / 256, 256, 0, stream>>>(x, W1, dis, h1b);
    gather1_kernel <<<N_NODES / 32, 256, 0, stream>>>(offs, endo, csr, h1b, b1, rs);
    gather2_pool_kernel<<<N_NODES / 32, 256, 0, stream>>>(offs, endo, csr, rs, W2, batch, sums);
    pool_finish_kernel <<<1, 64, 0, stream>>>(sums, batch, b2, out);
}

// Round 3
// 342.739 us; speedup vs baseline: 2.9189x; 1.0542x over previous
//
#include <hip/hip_runtime.h>
#include <math.h>

#define N_NODES 200000
#define N_EDGES 6400000
#define F_IN    128
#define H_HID   6
#define C_OUT   10
#define G_BATCH 64

#define TILE_E  8192                                 // edges per sort tile
#define NT      ((N_EDGES + TILE_E - 1) / TILE_E)    // 782 tiles
#define EPT     16                                   // consecutive edges per thread
#define BSH     9                                    // bucket = col >> 9
#define BNODES  512                                  // nodes per bucket
#define NBUCK   ((N_NODES + BNODES - 1) / BNODES)    // 391 buckets
#define BCAP    18432                                // slots per bucket (mean 16384, +16 sigma)

// ---- bf16 helpers (RNE) ---------------------------------------------------
__device__ __forceinline__ unsigned short f2bf(float f) {
    unsigned u = __float_as_uint(f);
    u += 0x7fff + ((u >> 16) & 1);
    return (unsigned short)(u >> 16);
}
__device__ __forceinline__ unsigned pack2(float a, float b) {
    return (unsigned)f2bf(a) | ((unsigned)f2bf(b) << 16);
}
__device__ __forceinline__ float bf_lo(unsigned u) { return __uint_as_float(u << 16); }
__device__ __forceinline__ float bf_hi(unsigned u) { return __uint_as_float(u & 0xffff0000u); }

// ---------------------------------------------------------------------------
// A) scatter with on-the-fly reservation: LDS-sort tile by bucket, reserve each
//    bucket's run via ONE global atomic, stream runs into fixed bucket regions.
//    Payload packed: (col&511)<<18 | row.
//    v3: int4 edge loads (thread owns 16 consecutive edges), bucket ids kept in
//    registers (no col re-read in placement), 3-barrier shfl scan (was 18).
__global__ __launch_bounds__(512, 8) void scatterA_kernel(const int* __restrict__ row,
                                                          const int* __restrict__ col,
                                                          int* __restrict__ gcur,
                                                          int* __restrict__ binned, int E) {
    __shared__ int sortbuf[TILE_E];   // 32 KB
    __shared__ int cnt[512];          // histogram, then placement cursor
    __shared__ int pos[513];          // exclusive prefix (bucket -> tile-local start)
    __shared__ int lbase[512];        // bucket -> global run base
    __shared__ int wtot[8];
    int t = blockIdx.x, tid = threadIdx.x;
    int base = t * TILE_E;
    int tile_n = min(TILE_E, E - base);

    cnt[tid] = 0;
    __syncthreads();

    // phase 0: vector-load 16 consecutive edges, histogram buckets, keep payload+bucket in regs
    int myval[EPT];
    int myb[EPT];
    int ebase = base + tid * EPT;
    if (ebase + EPT <= E) {
        const int4* c4 = (const int4*)(col + ebase);
        const int4* r4 = (const int4*)(row + ebase);
#pragma unroll
        for (int q = 0; q < EPT / 4; ++q) {
            int4 c = c4[q];
            int4 r = r4[q];
            int k = q * 4;
            myval[k + 0] = ((c.x & (BNODES - 1)) << 18) | r.x;  myb[k + 0] = c.x >> BSH;
            myval[k + 1] = ((c.y & (BNODES - 1)) << 18) | r.y;  myb[k + 1] = c.y >> BSH;
            myval[k + 2] = ((c.z & (BNODES - 1)) << 18) | r.z;  myb[k + 2] = c.z >> BSH;
            myval[k + 3] = ((c.w & (BNODES - 1)) << 18) | r.w;  myb[k + 3] = c.w >> BSH;
        }
#pragma unroll
        for (int k = 0; k < EPT; ++k) atomicAdd(&cnt[myb[k]], 1);
    } else {
#pragma unroll
        for (int k = 0; k < EPT; ++k) {
            int e = ebase + k;
            if (e < E) {
                int c = col[e];
                myval[k] = ((c & (BNODES - 1)) << 18) | row[e];
                myb[k] = c >> BSH;
                atomicAdd(&cnt[myb[k]], 1);
            } else {
                myb[k] = -1;
            }
        }
    }
    __syncthreads();

    // phase 1: shfl-based scan of 512 counts (3 barriers total)
    int c = cnt[tid];
    int v = c;
    int lane = tid & 63, wid = tid >> 6;
#pragma unroll
    for (int off = 1; off < 64; off <<= 1) {
        int u = __shfl_up(v, off);
        if (lane >= off) v += u;
    }
    if (lane == 63) wtot[wid] = v;
    __syncthreads();
    if (tid == 0) {
        int running = 0;
#pragma unroll
        for (int i = 0; i < 8; ++i) { int w = wtot[i]; wtot[i] = running; running += w; }
    }
    __syncthreads();
    int incl = v + wtot[wid];
    int excl = incl - c;
    pos[tid] = excl;
    cnt[tid] = excl;                  // becomes the placement cursor
    if (tid == 511) pos[512] = incl;
    if (tid < NBUCK) {                // reserve global space for this tile's run
        lbase[tid] = tid * BCAP + (c ? atomicAdd(&gcur[tid], c) : 0);
    }
    __syncthreads();

    // phase 2: place into LDS sort buffer — pure LDS, no global loads
#pragma unroll
    for (int k = 0; k < EPT; ++k) {
        if (myb[k] >= 0) {
            int p = atomicAdd(&cnt[myb[k]], 1);
            sortbuf[p] = myval[k];
        }
    }
    __syncthreads();

    // phase 3: streaming write-out; position -> bucket via LDS binary search
    for (int i = tid; i < tile_n; i += 512) {
        int lo = 0, hi = NBUCK - 1;
        while (lo < hi) {
            int mid = (lo + hi + 1) >> 1;
            if (pos[mid] <= i) lo = mid; else hi = mid - 1;
        }
        binned[lbase[lo] + (i - pos[lo])] = sortbuf[i];
    }
}

// B) per-bucket CSR, v3: FULL-bucket LDS staging (73.7 KB), 2 binned sweeps
//    (count + place), coalesced stream-out. 391 blocks, 2 blocks/CU, 32 waves.
__global__ __launch_bounds__(1024) void passB_kernel(const int* __restrict__ gcur,
                                                     const int* __restrict__ binned,
                                                     int* __restrict__ offs, int* __restrict__ endo,
                                                     float* __restrict__ dis,
                                                     int* __restrict__ csr, int E) {
    __shared__ int stage[BCAP];       // 73728 B
    __shared__ int cnt[512];          // histogram, then placement cursor
    __shared__ int wtot[8];
    int b = blockIdx.x, tid = threadIdx.x;
    int bb = b * BCAP;
    int total = gcur[b];
    int be = bb + total;
    if (tid < 512) cnt[tid] = 0;
    __syncthreads();

    // sweep 1: count (x4 unrolled for MLP)
    int e = bb + tid;
    for (; e + 3072 < be; e += 4096) {
        int p0 = binned[e], p1 = binned[e + 1024], p2 = binned[e + 2048], p3 = binned[e + 3072];
        atomicAdd(&cnt[p0 >> 18], 1); atomicAdd(&cnt[p1 >> 18], 1);
        atomicAdd(&cnt[p2 >> 18], 1); atomicAdd(&cnt[p3 >> 18], 1);
    }
    for (; e < be; e += 1024) atomicAdd(&cnt[binned[e] >> 18], 1);
    __syncthreads();

    // scan of 512 counts by the first 8 waves (shfl scan, 3 barriers)
    if (tid < 512) {
        int v0 = cnt[tid];
        int v = v0;
        int lane = tid & 63, wid = tid >> 6;
#pragma unroll
        for (int off = 1; off < 64; off <<= 1) {
            int u = __shfl_up(v, off);
            if (lane >= off) v += u;
        }
        if (lane == 63) wtot[wid] = v;
        __syncthreads();
        if (tid == 0) {
            int running = 0;
#pragma unroll
            for (int i = 0; i < 8; ++i) { int w = wtot[i]; wtot[i] = running; running += w; }
        }
        __syncthreads();
        int incl = v + wtot[wid];
        int excl = incl - v0;
        cnt[tid] = excl;              // becomes cursor
        int n = (b << BSH) + tid;
        if (n < N_NODES) {
            offs[n] = bb + excl;
            endo[n] = bb + excl + v0;
            dis[n] = rsqrtf((float)v0 + 1.0f);
        }
    } else {
        __syncthreads();
        __syncthreads();
    }
    __syncthreads();

    // sweep 2: place every edge into the full-bucket stage
    e = bb + tid;
    for (; e + 3072 < be; e += 4096) {
        int p0 = binned[e], p1 = binned[e + 1024], p2 = binned[e + 2048], p3 = binned[e + 3072];
        int s0 = atomicAdd(&cnt[p0 >> 18], 1); stage[s0] = p0 & 0x3FFFF;
        int s1 = atomicAdd(&cnt[p1 >> 18], 1); stage[s1] = p1 & 0x3FFFF;
        int s2 = atomicAdd(&cnt[p2 >> 18], 1); stage[s2] = p2 & 0x3FFFF;
        int s3 = atomicAdd(&cnt[p3 >> 18], 1); stage[s3] = p3 & 0x3FFFF;
    }
    for (; e < be; e += 1024) {
        int p = binned[e];
        int s = atomicAdd(&cnt[p >> 18], 1); stage[s] = p & 0x3FFFF;
    }
    __syncthreads();

    // coalesced stream-out
    for (int i = tid; i < total; i += 1024) csr[bb + i] = stage[i];
}

// ---------------------------------------------------------------------------
// xw1: h1b row (uint4) = { bf16(d*a0,d*a1), bf16(d*a2,d*a3), bf16(d*a4,d*a5), bits(d) }
__global__ void xw1_kernel(const float* __restrict__ x, const float* __restrict__ W1,
                           const float* __restrict__ dis, uint4* __restrict__ h1b) {
    __shared__ float w[F_IN * H_HID];
    for (int i = threadIdx.x; i < F_IN * H_HID; i += blockDim.x) w[i] = W1[i];
    __syncthreads();
    int n = blockIdx.x * blockDim.x + threadIdx.x;
    if (n >= N_NODES) return;
    float acc[H_HID] = {0.f, 0.f, 0.f, 0.f, 0.f, 0.f};
    const float4* xr = (const float4*)(x + (size_t)n * F_IN);
#pragma unroll 4
    for (int f4 = 0; f4 < F_IN / 4; ++f4) {
        float4 v = xr[f4];
        int f = f4 * 4;
#pragma unroll
        for (int j = 0; j < H_HID; ++j) {
            acc[j] += v.x * w[(f + 0) * H_HID + j] + v.y * w[(f + 1) * H_HID + j]
                    + v.z * w[(f + 2) * H_HID + j] + v.w * w[(f + 3) * H_HID + j];
        }
    }
    float d = dis[n];
    uint4 o;
    o.x = pack2(d * acc[0], d * acc[1]);
    o.y = pack2(d * acc[2], d * acc[3]);
    o.z = pack2(d * acc[4], d * acc[5]);
    o.w = __float_as_uint(d);
    h1b[n] = o;
}

// gather conv1: 8 lanes/node, 4-deep unroll (4 gathers in flight per lane).
__global__ void gather1_kernel(const int* __restrict__ offs, const int* __restrict__ endo,
                               const int* __restrict__ csr,
                               const uint4* __restrict__ h1b, const float* __restrict__ b1,
                               uint4* __restrict__ rs) {
    int grp = threadIdx.x >> 3, sub = threadIdx.x & 7;
    int n = blockIdx.x * 32 + grp;
    int s = offs[n], e_end = endo[n];
    float a[H_HID] = {0.f, 0.f, 0.f, 0.f, 0.f, 0.f};
    int e = s + sub;
    for (; e + 24 < e_end; e += 32) {
        int i0 = csr[e], i1 = csr[e + 8], i2 = csr[e + 16], i3 = csr[e + 24];
        uint4 v0 = h1b[i0], v1 = h1b[i1], v2 = h1b[i2], v3 = h1b[i3];
        a[0] += (bf_lo(v0.x) + bf_lo(v1.x)) + (bf_lo(v2.x) + bf_lo(v3.x));
        a[1] += (bf_hi(v0.x) + bf_hi(v1.x)) + (bf_hi(v2.x) + bf_hi(v3.x));
        a[2] += (bf_lo(v0.y) + bf_lo(v1.y)) + (bf_lo(v2.y) + bf_lo(v3.y));
        a[3] += (bf_hi(v0.y) + bf_hi(v1.y)) + (bf_hi(v2.y) + bf_hi(v3.y));
        a[4] += (bf_lo(v0.z) + bf_lo(v1.z)) + (bf_lo(v2.z) + bf_lo(v3.z));
        a[5] += (bf_hi(v0.z) + bf_hi(v1.z)) + (bf_hi(v2.z) + bf_hi(v3.z));
    }
    for (; e < e_end; e += 8) {
        uint4 v = h1b[csr[e]];
        a[0] += bf_lo(v.x); a[1] += bf_hi(v.x);
        a[2] += bf_lo(v.y); a[3] += bf_hi(v.y);
        a[4] += bf_lo(v.z); a[5] += bf_hi(v.z);
    }
#pragma unroll
    for (int j = 0; j < H_HID; ++j)
#pragma unroll
        for (int off = 4; off > 0; off >>= 1) a[j] += __shfl_xor(a[j], off);
    uint4 self = h1b[n];
    float d = __uint_as_float(self.w);
    float sf[H_HID] = {bf_lo(self.x), bf_hi(self.x), bf_lo(self.y),
                       bf_hi(self.y), bf_lo(self.z), bf_hi(self.z)};
    if (sub == 0) {
        float r[H_HID];
#pragma unroll
        for (int j = 0; j < H_HID; ++j) {
            float vv = d * (a[j] + sf[j]) + b1[j];
            r[j] = d * (vv > 0.f ? vv : 0.f);    // pre-scaled for layer 2
        }
        uint4 o;
        o.x = pack2(r[0], r[1]);
        o.y = pack2(r[2], r[3]);
        o.z = pack2(r[4], r[5]);
        o.w = self.w;
        rs[n] = o;
    }
}

// gather conv2 (6ch) + W2 post-aggregation + fused pooling. 8 lanes/node.
__global__ void gather2_pool_kernel(const int* __restrict__ offs, const int* __restrict__ endo,
                                    const int* __restrict__ csr,
                                    const uint4* __restrict__ rs, const float* __restrict__ W2,
                                    const int* __restrict__ batch, float* __restrict__ sums) {
    __shared__ float w2s[H_HID * C_OUT];
    __shared__ float nodeval[32][C_OUT];
    __shared__ int lg[32];
    if (threadIdx.x < H_HID * C_OUT) w2s[threadIdx.x] = W2[threadIdx.x];
    __syncthreads();
    int grp = threadIdx.x >> 3, sub = threadIdx.x & 7;
    int n = blockIdx.x * 32 + grp;
    int s = offs[n], e_end = endo[n];
    float a[H_HID] = {0.f, 0.f, 0.f, 0.f, 0.f, 0.f};
    int e = s + sub;
    for (; e + 24 < e_end; e += 32) {
        int i0 = csr[e], i1 = csr[e + 8], i2 = csr[e + 16], i3 = csr[e + 24];
        uint4 v0 = rs[i0], v1 = rs[i1], v2 = rs[i2], v3 = rs[i3];
        a[0] += (bf_lo(v0.x) + bf_lo(v1.x)) + (bf_lo(v2.x) + bf_lo(v3.x));
        a[1] += (bf_hi(v0.x) + bf_hi(v1.x)) + (bf_hi(v2.x) + bf_hi(v3.x));
        a[2] += (bf_lo(v0.y) + bf_lo(v1.y)) + (bf_lo(v2.y) + bf_lo(v3.y));
        a[3] += (bf_hi(v0.y) + bf_hi(v1.y)) + (bf_hi(v2.y) + bf_hi(v3.y));
        a[4] += (bf_lo(v0.z) + bf_lo(v1.z)) + (bf_lo(v2.z) + bf_lo(v3.z));
        a[5] += (bf_hi(v0.z) + bf_hi(v1.z)) + (bf_hi(v2.z) + bf_hi(v3.z));
    }
    for (; e < e_end; e += 8) {
        uint4 v = rs[csr[e]];
        a[0] += bf_lo(v.x); a[1] += bf_hi(v.x);
        a[2] += bf_lo(v.y); a[3] += bf_hi(v.y);
        a[4] += bf_lo(v.z); a[5] += bf_hi(v.z);
    }
#pragma unroll
    for (int j = 0; j < H_HID; ++j)
#pragma unroll
        for (int off = 4; off > 0; off >>= 1) a[j] += __shfl_xor(a[j], off);
    uint4 self = rs[n];
    float d = __uint_as_float(self.w);
    float t[H_HID] = {a[0] + bf_lo(self.x), a[1] + bf_hi(self.x), a[2] + bf_lo(self.y),
                      a[3] + bf_hi(self.y), a[4] + bf_lo(self.z), a[5] + bf_hi(self.z)};
    {   // all 8 lanes hold the full sum after xor-reduce
        float acc = 0.f;
#pragma unroll
        for (int j = 0; j < H_HID; ++j) acc += t[j] * w2s[j * C_OUT + sub];
        nodeval[grp][sub] = d * acc;
        if (sub < 2) {
            float acc2 = 0.f;
#pragma unroll
            for (int j = 0; j < H_HID; ++j) acc2 += t[j] * w2s[j * C_OUT + sub + 8];
            nodeval[grp][sub + 8] = d * acc2;
        }
    }
    if (sub == 0) lg[grp] = batch[n];
    __syncthreads();
    if (threadIdx.x < C_OUT) {
        int c = threadIdx.x;
        float acc = 0.f;
        int gcur2 = lg[0];
#pragma unroll
        for (int w = 0; w < 32; ++w) {
            if (lg[w] != gcur2) {
                atomicAdd(&sums[gcur2 * C_OUT + c], acc);
                gcur2 = lg[w]; acc = 0.f;
            }
            acc += nodeval[w][c];
        }
        atomicAdd(&sums[gcur2 * C_OUT + c], acc);
    }
}

// mean (counts via binary search on sorted batch) + b2 + log_softmax
__global__ void pool_finish_kernel(const float* __restrict__ sums, const int* __restrict__ batch,
                                   const float* __restrict__ b2, float* __restrict__ out) {
    int g = threadIdx.x;
    if (g >= G_BATCH) return;
    int lo = 0, hi = N_NODES;
    while (lo < hi) { int mid = (lo + hi) >> 1; if (batch[mid] < g) lo = mid + 1; else hi = mid; }
    int c0 = lo;
    hi = N_NODES;
    while (lo < hi) { int mid = (lo + hi) >> 1; if (batch[mid] < g + 1) lo = mid + 1; else hi = mid; }
    float inv = 1.0f / fmaxf((float)(lo - c0), 1.0f);
    float v[C_OUT], m = -INFINITY;
#pragma unroll
    for (int c = 0; c < C_OUT; ++c) {
        v[c] = sums[g * C_OUT + c] * inv + b2[c];
        m = fmaxf(m, v[c]);
    }
    float s = 0.f;
#pragma unroll
    for (int c = 0; c < C_OUT; ++c) s += expf(v[c] - m);
    float lse = m + logf(s);
#pragma unroll
    for (int c = 0; c < C_OUT; ++c) out[g * C_OUT + c] = v[c] - lse;
}

extern "C" void kernel_launch(void* const* d_in, const int* in_sizes, int n_in,
                              void* d_out, int out_size, void* d_ws, size_t ws_size,
                              hipStream_t stream) {
    const float* x   = (const float*)d_in[0];
    const int* ei    = (const int*)d_in[1];
    const int* row   = ei;
    const int* col   = ei + N_EDGES;
    const int* batch = (const int*)d_in[2];
    const float* W1  = (const float*)d_in[3];
    const float* b1  = (const float*)d_in[4];
    const float* W2  = (const float*)d_in[5];
    const float* b2  = (const float*)d_in[6];
    float* out = (float*)d_out;

    // workspace layout — region sizes multiples of 16 B so uint4 arrays stay aligned
    char* p = (char*)d_ws;
    float* sums   = (float*)p;  p += (size_t)G_BATCH * C_OUT * 4;       // [zero] 2560B
    int*   gcur   = (int*)p;    p += (size_t)400 * 4;                   // [zero] 1600B (391 used)
    int*   offs   = (int*)p;    p += (size_t)N_NODES * 4;               // 800000B
    int*   endo   = (int*)p;    p += (size_t)N_NODES * 4;               // 800000B
    float* dis    = (float*)p;  p += (size_t)N_NODES * 4;               // 800000B
    int*   csr    = (int*)p;    p += (size_t)NBUCK * BCAP * 4;          // 28.8MB (gapped layout)
    int*   binned = (int*)p;                                            // 28.8MB, dead after passB
    uint4* h1b    = (uint4*)binned;                                     // 3.2MB, aliases binned
    uint4* rs     = (uint4*)binned + N_NODES;                           // 3.2MB

    hipMemsetAsync(sums, 0, (size_t)G_BATCH * C_OUT * 4 + 400 * 4, stream);   // sums + gcur

    scatterA_kernel<<<NT, 512, 0, stream>>>(row, col, gcur, binned, N_EDGES);
    passB_kernel   <<<NBUCK, 1024, 0, stream>>>(gcur, binned, offs, endo, dis, csr, N_EDGES);
    xw1_kernel     <<<(N_NODES + 255) / 256, 256, 0, stream>>>(x, W1, dis, h1b);
    gather1_kernel <<<N_NODES / 32, 256, 0, stream>>>(offs, endo, csr, h1b, b1, rs);
    gather2_pool_kernel<<<N_NODES / 32, 256, 0, stream>>>(offs, endo, csr, rs, W2, batch, sums);
    pool_finish_kernel <<<1, 64, 0, stream>>>(sums, batch, b2, out);
}

// Round 4
// 319.596 us; speedup vs baseline: 3.1303x; 1.0724x over previous
//
#include <hip/hip_runtime.h>
#include <math.h>

#define N_NODES 200000
#define N_EDGES 6400000
#define F_IN    128
#define H_HID   6
#define C_OUT   10
#define G_BATCH 64

#define TILE_E  8192                                 // edges per sort tile
#define NT      ((N_EDGES + TILE_E - 1) / TILE_E)    // 782 tiles
#define EPT     16                                   // consecutive edges per thread
#define BSH     9                                    // bucket = col >> 9
#define BNODES  512                                  // nodes per bucket
#define NBUCK   ((N_NODES + BNODES - 1) / BNODES)    // 391 buckets
#define BCAP    17408                                // slots/bucket (mean 16384, +8 sigma)
#define XBLK    512                                  // nodes per xw1acc block
#define NXB     ((N_NODES + XBLK - 1) / XBLK)        // 391

// ---- bf16 helpers (RNE) ---------------------------------------------------
__device__ __forceinline__ unsigned short f2bf(float f) {
    unsigned u = __float_as_uint(f);
    u += 0x7fff + ((u >> 16) & 1);
    return (unsigned short)(u >> 16);
}
__device__ __forceinline__ unsigned pack2(float a, float b) {
    return (unsigned)f2bf(a) | ((unsigned)f2bf(b) << 16);
}
__device__ __forceinline__ float bf_lo(unsigned u) { return __uint_as_float(u << 16); }
__device__ __forceinline__ float bf_hi(unsigned u) { return __uint_as_float(u & 0xffff0000u); }

// ---------------------------------------------------------------------------
// megaA: role-switched. Blocks [0,NT): edge scatter (round-3 proven body).
//        Blocks [NT,NT+NXB): xacc = x @ W1 (raw fp32, SoA) — overlaps the
//        latency-bound scatter with a BW-bound stream (wave-level co-schedule).
__global__ __launch_bounds__(512, 8) void megaA_kernel(const int* __restrict__ row,
                                                       const int* __restrict__ col,
                                                       const float* __restrict__ x,
                                                       const float* __restrict__ W1,
                                                       int* __restrict__ gcur,
                                                       int* __restrict__ binned,
                                                       float* __restrict__ xacc, int E) {
    __shared__ int sortbuf[TILE_E];   // 32 KB (xw1 role aliases first 3KB as W1 cache)
    __shared__ int cnt[512];
    __shared__ int pos[513];
    __shared__ int lbase[512];
    __shared__ int wtot[8];
    int tid = threadIdx.x;

    if (blockIdx.x >= NT) {
        // ---- xw1acc role ----
        float* w = (float*)sortbuf;
        for (int i = tid; i < F_IN * H_HID; i += 512) w[i] = W1[i];
        __syncthreads();
        int n = (blockIdx.x - NT) * XBLK + tid;
        if (n >= N_NODES) return;
        float acc[H_HID] = {0.f, 0.f, 0.f, 0.f, 0.f, 0.f};
        const float4* xr = (const float4*)(x + (size_t)n * F_IN);
#pragma unroll 4
        for (int f4 = 0; f4 < F_IN / 4; ++f4) {
            float4 v = xr[f4];
            int f = f4 * 4;
#pragma unroll
            for (int j = 0; j < H_HID; ++j) {
                acc[j] += v.x * w[(f + 0) * H_HID + j] + v.y * w[(f + 1) * H_HID + j]
                        + v.z * w[(f + 2) * H_HID + j] + v.w * w[(f + 3) * H_HID + j];
            }
        }
#pragma unroll
        for (int j = 0; j < H_HID; ++j) xacc[j * N_NODES + n] = acc[j];
        return;
    }

    // ---- scatter role (unchanged from round 3) ----
    int t = blockIdx.x;
    int base = t * TILE_E;
    int tile_n = min(TILE_E, E - base);

    cnt[tid] = 0;
    __syncthreads();

    int myval[EPT];
    int myb[EPT];
    int ebase = base + tid * EPT;
    if (ebase + EPT <= E) {
        const int4* c4 = (const int4*)(col + ebase);
        const int4* r4 = (const int4*)(row + ebase);
#pragma unroll
        for (int q = 0; q < EPT / 4; ++q) {
            int4 c = c4[q];
            int4 r = r4[q];
            int k = q * 4;
            myval[k + 0] = ((c.x & (BNODES - 1)) << 18) | r.x;  myb[k + 0] = c.x >> BSH;
            myval[k + 1] = ((c.y & (BNODES - 1)) << 18) | r.y;  myb[k + 1] = c.y >> BSH;
            myval[k + 2] = ((c.z & (BNODES - 1)) << 18) | r.z;  myb[k + 2] = c.z >> BSH;
            myval[k + 3] = ((c.w & (BNODES - 1)) << 18) | r.w;  myb[k + 3] = c.w >> BSH;
        }
#pragma unroll
        for (int k = 0; k < EPT; ++k) atomicAdd(&cnt[myb[k]], 1);
    } else {
#pragma unroll
        for (int k = 0; k < EPT; ++k) {
            int e = ebase + k;
            if (e < E) {
                int c = col[e];
                myval[k] = ((c & (BNODES - 1)) << 18) | row[e];
                myb[k] = c >> BSH;
                atomicAdd(&cnt[myb[k]], 1);
            } else {
                myb[k] = -1;
            }
        }
    }
    __syncthreads();

    int c = cnt[tid];
    int v = c;
    int lane = tid & 63, wid = tid >> 6;
#pragma unroll
    for (int off = 1; off < 64; off <<= 1) {
        int u = __shfl_up(v, off);
        if (lane >= off) v += u;
    }
    if (lane == 63) wtot[wid] = v;
    __syncthreads();
    if (tid == 0) {
        int running = 0;
#pragma unroll
        for (int i = 0; i < 8; ++i) { int w2 = wtot[i]; wtot[i] = running; running += w2; }
    }
    __syncthreads();
    int incl = v + wtot[wid];
    int excl = incl - c;
    pos[tid] = excl;
    cnt[tid] = excl;
    if (tid == 511) pos[512] = incl;
    if (tid < NBUCK) {
        lbase[tid] = tid * BCAP + (c ? atomicAdd(&gcur[tid], c) : 0);
    }
    __syncthreads();

#pragma unroll
    for (int k = 0; k < EPT; ++k) {
        if (myb[k] >= 0) {
            int p = atomicAdd(&cnt[myb[k]], 1);
            sortbuf[p] = myval[k];
        }
    }
    __syncthreads();

    for (int i = tid; i < tile_n; i += 512) {
        int lo = 0, hi = NBUCK - 1;
        while (lo < hi) {
            int mid = (lo + hi + 1) >> 1;
            if (pos[mid] <= i) lo = mid; else hi = mid - 1;
        }
        binned[lbase[lo] + (i - pos[lo])] = sortbuf[i];
    }
}

// ---------------------------------------------------------------------------
// passB2: per-bucket degree count -> d = rsqrt(deg+1); d-scale xacc, pack bf16
// into h1b. Node-local, fully coalesced. Replaces passB + xw1's d-dependence.
__global__ __launch_bounds__(1024) void passB2_kernel(const int* __restrict__ gcur,
                                                      const int* __restrict__ binned,
                                                      const float* __restrict__ xacc,
                                                      uint4* __restrict__ h1b) {
    __shared__ int cnt[512];
    int b = blockIdx.x, tid = threadIdx.x;
    int bb = b * BCAP, be = bb + gcur[b];
    if (tid < 512) cnt[tid] = 0;
    __syncthreads();
    int e = bb + tid;
    for (; e + 3072 < be; e += 4096) {
        int p0 = binned[e], p1 = binned[e + 1024], p2 = binned[e + 2048], p3 = binned[e + 3072];
        atomicAdd(&cnt[p0 >> 18], 1); atomicAdd(&cnt[p1 >> 18], 1);
        atomicAdd(&cnt[p2 >> 18], 1); atomicAdd(&cnt[p3 >> 18], 1);
    }
    for (; e < be; e += 1024) atomicAdd(&cnt[binned[e] >> 18], 1);
    __syncthreads();
    if (tid < 512) {
        int n = (b << BSH) + tid;
        if (n < N_NODES) {
            float d = rsqrtf((float)cnt[tid] + 1.0f);
            float a0 = xacc[0 * N_NODES + n], a1 = xacc[1 * N_NODES + n];
            float a2 = xacc[2 * N_NODES + n], a3 = xacc[3 * N_NODES + n];
            float a4 = xacc[4 * N_NODES + n], a5 = xacc[5 * N_NODES + n];
            uint4 o;
            o.x = pack2(d * a0, d * a1);
            o.y = pack2(d * a2, d * a3);
            o.z = pack2(d * a4, d * a5);
            o.w = __float_as_uint(d);
            h1b[n] = o;
        }
    }
}

// ---- shared sort-in-LDS prologue for BG kernels (count + scan + place) -----
// On exit: stage[] holds src indices sorted by local dst node; cnt[l] = END
// offset of node l's run (start = cnt[l-1], or 0 for l==0).
#define BG_SORT()                                                               \
    int bb = b * BCAP, be = bb + gcur[b];                                       \
    if (tid < 512) cnt[tid] = 0;                                                \
    __syncthreads();                                                            \
    {                                                                           \
        int e = bb + tid;                                                       \
        for (; e + 3072 < be; e += 4096) {                                      \
            int p0 = binned[e], p1 = binned[e + 1024];                          \
            int p2 = binned[e + 2048], p3 = binned[e + 3072];                   \
            atomicAdd(&cnt[p0 >> 18], 1); atomicAdd(&cnt[p1 >> 18], 1);         \
            atomicAdd(&cnt[p2 >> 18], 1); atomicAdd(&cnt[p3 >> 18], 1);         \
        }                                                                       \
        for (; e < be; e += 1024) atomicAdd(&cnt[binned[e] >> 18], 1);          \
    }                                                                           \
    __syncthreads();                                                            \
    {                                                                           \
        int v0 = (tid < 512) ? cnt[tid] : 0;                                    \
        int v = v0;                                                             \
        int lane = tid & 63, wid = tid >> 6;                                    \
        _Pragma("unroll")                                                       \
        for (int off = 1; off < 64; off <<= 1) {                                \
            int u = __shfl_up(v, off);                                          \
            if (lane >= off) v += u;                                            \
        }                                                                       \
        if (wid < 8 && lane == 63) wtot[wid] = v;                               \
        __syncthreads();                                                        \
        if (tid == 0) {                                                         \
            int running = 0;                                                    \
            _Pragma("unroll")                                                   \
            for (int i = 0; i < 8; ++i) { int w2 = wtot[i]; wtot[i] = running; running += w2; } \
        }                                                                       \
        __syncthreads();                                                        \
        if (tid < 512) cnt[tid] = v + wtot[wid] - v0;                           \
    }                                                                           \
    __syncthreads();                                                            \
    {                                                                           \
        int e = bb + tid;                                                       \
        for (; e + 3072 < be; e += 4096) {                                      \
            int p0 = binned[e], p1 = binned[e + 1024];                          \
            int p2 = binned[e + 2048], p3 = binned[e + 3072];                   \
            int s0 = atomicAdd(&cnt[p0 >> 18], 1); stage[s0] = p0 & 0x3FFFF;    \
            int s1 = atomicAdd(&cnt[p1 >> 18], 1); stage[s1] = p1 & 0x3FFFF;    \
            int s2 = atomicAdd(&cnt[p2 >> 18], 1); stage[s2] = p2 & 0x3FFFF;    \
            int s3 = atomicAdd(&cnt[p3 >> 18], 1); stage[s3] = p3 & 0x3FFFF;    \
        }                                                                       \
        for (; e < be; e += 1024) {                                             \
            int p = binned[e];                                                  \
            int s = atomicAdd(&cnt[p >> 18], 1); stage[s] = p & 0x3FFFF;        \
        }                                                                       \
    }                                                                           \
    __syncthreads();

#define GATHER_BODY(TBL)                                                        \
    float a[H_HID] = {0.f, 0.f, 0.f, 0.f, 0.f, 0.f};                            \
    {                                                                           \
        int ee = s + sub;                                                       \
        for (; ee + 24 < e_end; ee += 32) {                                     \
            int i0 = stage[ee], i1 = stage[ee + 8];                             \
            int i2 = stage[ee + 16], i3 = stage[ee + 24];                       \
            uint4 v0 = TBL[i0], v1 = TBL[i1], v2 = TBL[i2], v3 = TBL[i3];       \
            a[0] += (bf_lo(v0.x) + bf_lo(v1.x)) + (bf_lo(v2.x) + bf_lo(v3.x));  \
            a[1] += (bf_hi(v0.x) + bf_hi(v1.x)) + (bf_hi(v2.x) + bf_hi(v3.x));  \
            a[2] += (bf_lo(v0.y) + bf_lo(v1.y)) + (bf_lo(v2.y) + bf_lo(v3.y));  \
            a[3] += (bf_hi(v0.y) + bf_hi(v1.y)) + (bf_hi(v2.y) + bf_hi(v3.y));  \
            a[4] += (bf_lo(v0.z) + bf_lo(v1.z)) + (bf_lo(v2.z) + bf_lo(v3.z));  \
            a[5] += (bf_hi(v0.z) + bf_hi(v1.z)) + (bf_hi(v2.z) + bf_hi(v3.z));  \
        }                                                                       \
        for (; ee < e_end; ee += 8) {                                           \
            uint4 vv = TBL[stage[ee]];                                          \
            a[0] += bf_lo(vv.x); a[1] += bf_hi(vv.x);                           \
            a[2] += bf_lo(vv.y); a[3] += bf_hi(vv.y);                           \
            a[4] += bf_lo(vv.z); a[5] += bf_hi(vv.z);                           \
        }                                                                       \
    }                                                                           \
    _Pragma("unroll")                                                           \
    for (int j = 0; j < H_HID; ++j) {                                           \
        _Pragma("unroll")                                                       \
        for (int off = 4; off > 0; off >>= 1) a[j] += __shfl_xor(a[j], off);    \
    }

// ---------------------------------------------------------------------------
// BG1: sort bucket into LDS, then layer-1 gather (indices from LDS, h1b from
// L2), finalize (self term + bias + ReLU + pre-scale), write rs. No CSR.
__global__ __launch_bounds__(1024) void bg1_kernel(const int* __restrict__ gcur,
                                                   const int* __restrict__ binned,
                                                   const uint4* __restrict__ h1b,
                                                   const float* __restrict__ b1,
                                                   uint4* __restrict__ rs) {
    __shared__ int stage[BCAP];       // 68 KB
    __shared__ int cnt[512];
    __shared__ int wtot[8];
    int b = blockIdx.x, tid = threadIdx.x;
    BG_SORT()

    int sub = tid & 7, grp = tid >> 3;       // 128 node-groups x 8 lanes
    for (int ch = 0; ch < 4; ++ch) {
        int ln = ch * 128 + grp;
        int n = (b << BSH) + ln;
        int s = ln ? cnt[ln - 1] : 0;
        int e_end = cnt[ln];
        GATHER_BODY(h1b)
        if (sub == 0 && n < N_NODES) {
            uint4 self = h1b[n];
            float d = __uint_as_float(self.w);
            float sf[H_HID] = {bf_lo(self.x), bf_hi(self.x), bf_lo(self.y),
                               bf_hi(self.y), bf_lo(self.z), bf_hi(self.z)};
            float r[H_HID];
#pragma unroll
            for (int j = 0; j < H_HID; ++j) {
                float vv = d * (a[j] + sf[j]) + b1[j];
                r[j] = d * (vv > 0.f ? vv : 0.f);    // pre-scaled for layer 2
            }
            uint4 o;
            o.x = pack2(r[0], r[1]);
            o.y = pack2(r[2], r[3]);
            o.z = pack2(r[4], r[5]);
            o.w = self.w;
            rs[n] = o;
        }
    }
}

// ---------------------------------------------------------------------------
// BG2: sort + layer-2 gather + W2 + hierarchical pool. A 512-node block spans
// <=2 graphs (graphs ~3125 nodes) -> LDS partials, 20 global atomics/block.
__global__ __launch_bounds__(1024) void bg2_kernel(const int* __restrict__ gcur,
                                                   const int* __restrict__ binned,
                                                   const uint4* __restrict__ rs,
                                                   const float* __restrict__ W2,
                                                   const int* __restrict__ batch,
                                                   float* __restrict__ sums) {
    __shared__ int stage[BCAP];       // 68 KB
    __shared__ int cnt[512];
    __shared__ int wtot[8];
    __shared__ float w2s[H_HID * C_OUT];
    __shared__ float nv[128][C_OUT + 1];
    __shared__ int lg[128];
    __shared__ float gacc[2][C_OUT];
    __shared__ int sg0;
    int b = blockIdx.x, tid = threadIdx.x;
    if (tid < H_HID * C_OUT) w2s[tid] = W2[tid];
    if (tid < 2 * C_OUT) ((float*)gacc)[tid] = 0.f;
    if (tid == 0) sg0 = batch[b << BSH];
    BG_SORT()

    int sub = tid & 7, grp = tid >> 3;
    for (int ch = 0; ch < 4; ++ch) {
        int ln = ch * 128 + grp;
        int n = (b << BSH) + ln;
        int s = ln ? cnt[ln - 1] : 0;
        int e_end = cnt[ln];
        GATHER_BODY(rs)
        uint4 self = {0u, 0u, 0u, 0u};
        if (n < N_NODES) self = rs[n];
        float d = (n < N_NODES) ? __uint_as_float(self.w) : 0.f;
        float t[H_HID] = {a[0] + bf_lo(self.x), a[1] + bf_hi(self.x),
                          a[2] + bf_lo(self.y), a[3] + bf_hi(self.y),
                          a[4] + bf_lo(self.z), a[5] + bf_hi(self.z)};
        {
            float accv = 0.f;
#pragma unroll
            for (int j = 0; j < H_HID; ++j) accv += t[j] * w2s[j * C_OUT + sub];
            nv[grp][sub] = d * accv;
            if (sub < 2) {
                float accv2 = 0.f;
#pragma unroll
                for (int j = 0; j < H_HID; ++j) accv2 += t[j] * w2s[j * C_OUT + sub + 8];
                nv[grp][sub + 8] = d * accv2;
            }
        }
        if (sub == 0) lg[grp] = (n < N_NODES) ? batch[n] : sg0;
        __syncthreads();
        // 8 segments x 10 channels walk 16 entries each -> LDS partials
        if (tid < 80) {
            int seg = tid / C_OUT, cc = tid - seg * C_OUT;
            int g = -1; float av = 0.f;
            for (int i = 0; i < 16; ++i) {
                int wdx = seg * 16 + i;
                int gw = lg[wdx];
                if (gw != g) {
                    if (g >= 0) {
                        int r2 = g - sg0;
                        if (r2 < 2) atomicAdd(&gacc[r2][cc], av);
                        else atomicAdd(&sums[g * C_OUT + cc], av);
                    }
                    g = gw; av = 0.f;
                }
                av += nv[wdx][cc];
            }
            int r2 = g - sg0;
            if (r2 < 2) atomicAdd(&gacc[r2][cc], av);
            else atomicAdd(&sums[g * C_OUT + cc], av);
        }
        __syncthreads();
    }
    if (tid < 2 * C_OUT) {
        int r2 = tid / C_OUT, cc = tid - r2 * C_OUT;
        int g = sg0 + r2;
        if (g < G_BATCH) atomicAdd(&sums[g * C_OUT + cc], gacc[r2][cc]);
    }
}

// mean (counts via binary search on sorted batch) + b2 + log_softmax
__global__ void pool_finish_kernel(const float* __restrict__ sums, const int* __restrict__ batch,
                                   const float* __restrict__ b2, float* __restrict__ out) {
    int g = threadIdx.x;
    if (g >= G_BATCH) return;
    int lo = 0, hi = N_NODES;
    while (lo < hi) { int mid = (lo + hi) >> 1; if (batch[mid] < g) lo = mid + 1; else hi = mid; }
    int c0 = lo;
    hi = N_NODES;
    while (lo < hi) { int mid = (lo + hi) >> 1; if (batch[mid] < g + 1) lo = mid + 1; else hi = mid; }
    float inv = 1.0f / fmaxf((float)(lo - c0), 1.0f);
    float v[C_OUT], m = -INFINITY;
#pragma unroll
    for (int c = 0; c < C_OUT; ++c) {
        v[c] = sums[g * C_OUT + c] * inv + b2[c];
        m = fmaxf(m, v[c]);
    }
    float s = 0.f;
#pragma unroll
    for (int c = 0; c < C_OUT; ++c) s += expf(v[c] - m);
    float lse = m + logf(s);
#pragma unroll
    for (int c = 0; c < C_OUT; ++c) out[g * C_OUT + c] = v[c] - lse;
}

extern "C" void kernel_launch(void* const* d_in, const int* in_sizes, int n_in,
                              void* d_out, int out_size, void* d_ws, size_t ws_size,
                              hipStream_t stream) {
    const float* x   = (const float*)d_in[0];
    const int* ei    = (const int*)d_in[1];
    const int* row   = ei;
    const int* col   = ei + N_EDGES;
    const int* batch = (const int*)d_in[2];
    const float* W1  = (const float*)d_in[3];
    const float* b1  = (const float*)d_in[4];
    const float* W2  = (const float*)d_in[5];
    const float* b2  = (const float*)d_in[6];
    float* out = (float*)d_out;

    // workspace layout — region sizes multiples of 16 B so uint4 arrays stay aligned
    char* p = (char*)d_ws;
    float* sums   = (float*)p;  p += (size_t)G_BATCH * C_OUT * 4;       // [zero] 2560B
    int*   gcur   = (int*)p;    p += (size_t)400 * 4;                   // [zero] 1600B (391 used)
    int*   binned = (int*)p;    p += (size_t)NBUCK * BCAP * 4;          // 27.2MB (gapped layout)
    float* xacc   = (float*)p;  p += (size_t)H_HID * N_NODES * 4;       // 4.8MB SoA
    uint4* h1b    = (uint4*)p;  p += (size_t)N_NODES * 16;              // 3.2MB
    uint4* rs     = (uint4*)p;                                          // 3.2MB

    hipMemsetAsync(sums, 0, (size_t)G_BATCH * C_OUT * 4 + 400 * 4, stream);   // sums + gcur

    megaA_kernel  <<<NT + NXB, 512, 0, stream>>>(row, col, x, W1, gcur, binned, xacc, N_EDGES);
    passB2_kernel <<<NBUCK, 1024, 0, stream>>>(gcur, binned, xacc, h1b);
    bg1_kernel    <<<NBUCK, 1024, 0, stream>>>(gcur, binned, h1b, b1, rs);
    bg2_kernel    <<<NBUCK, 1024, 0, stream>>>(gcur, binned, rs, W2, batch, sums);
    pool_finish_kernel<<<1, 64, 0, stream>>>(sums, batch, b2, out);
}

// Round 6
// 319.156 us; speedup vs baseline: 3.1346x; 1.0014x over previous
//
#include <hip/hip_runtime.h>
#include <math.h>

#define N_NODES 200000
#define N_EDGES 6400000
#define F_IN    128
#define H_HID   6
#define C_OUT   10
#define G_BATCH 64

#define TILE_E  8192                                 // edges per sort tile
#define NT      ((N_EDGES + TILE_E - 1) / TILE_E)    // 782 tiles
#define EPT     16                                   // consecutive edges per thread
#define BSH     9                                    // bucket = col >> 9
#define BNODES  512                                  // nodes per bucket
#define NBUCK   ((N_NODES + BNODES - 1) / BNODES)    // 391 buckets
#define BCAP    17408                                // slots/bucket (mean 16384, +8 sigma)
#define XBLK    512                                  // nodes per xw1acc block
#define NXB     ((N_NODES + XBLK - 1) / XBLK)        // 391

// ---- bf16 helpers (RNE) ---------------------------------------------------
__device__ __forceinline__ unsigned short f2bf(float f) {
    unsigned u = __float_as_uint(f);
    u += 0x7fff + ((u >> 16) & 1);
    return (unsigned short)(u >> 16);
}
__device__ __forceinline__ unsigned pack2(float a, float b) {
    return (unsigned)f2bf(a) | ((unsigned)f2bf(b) << 16);
}
__device__ __forceinline__ float bf_lo(unsigned u) { return __uint_as_float(u << 16); }
__device__ __forceinline__ float bf_hi(unsigned u) { return __uint_as_float(u & 0xffff0000u); }

// ---------------------------------------------------------------------------
// megaA: role-switched. Blocks [0,NT): edge scatter. Blocks [NT,NT+NXB):
// xacc = x @ W1 (raw fp32, SoA). (round-4 body, unchanged, verified)
__global__ __launch_bounds__(512, 8) void megaA_kernel(const int* __restrict__ row,
                                                       const int* __restrict__ col,
                                                       const float* __restrict__ x,
                                                       const float* __restrict__ W1,
                                                       int* __restrict__ gcur,
                                                       int* __restrict__ binned,
                                                       float* __restrict__ xacc, int E) {
    __shared__ int sortbuf[TILE_E];   // 32 KB (xw1 role aliases first 3KB as W1 cache)
    __shared__ int cnt[512];
    __shared__ int pos[513];
    __shared__ int lbase[512];
    __shared__ int wtot[8];
    int tid = threadIdx.x;

    if (blockIdx.x >= NT) {
        // ---- xw1acc role ----
        float* w = (float*)sortbuf;
        for (int i = tid; i < F_IN * H_HID; i += 512) w[i] = W1[i];
        __syncthreads();
        int n = (blockIdx.x - NT) * XBLK + tid;
        if (n >= N_NODES) return;
        float acc[H_HID] = {0.f, 0.f, 0.f, 0.f, 0.f, 0.f};
        const float4* xr = (const float4*)(x + (size_t)n * F_IN);
#pragma unroll 4
        for (int f4 = 0; f4 < F_IN / 4; ++f4) {
            float4 v = xr[f4];
            int f = f4 * 4;
#pragma unroll
            for (int j = 0; j < H_HID; ++j) {
                acc[j] += v.x * w[(f + 0) * H_HID + j] + v.y * w[(f + 1) * H_HID + j]
                        + v.z * w[(f + 2) * H_HID + j] + v.w * w[(f + 3) * H_HID + j];
            }
        }
#pragma unroll
        for (int j = 0; j < H_HID; ++j) xacc[j * N_NODES + n] = acc[j];
        return;
    }

    // ---- scatter role ----
    int t = blockIdx.x;
    int base = t * TILE_E;
    int tile_n = min(TILE_E, E - base);

    cnt[tid] = 0;
    __syncthreads();

    int myval[EPT];
    int myb[EPT];
    int ebase = base + tid * EPT;
    if (ebase + EPT <= E) {
        const int4* c4 = (const int4*)(col + ebase);
        const int4* r4 = (const int4*)(row + ebase);
#pragma unroll
        for (int q = 0; q < EPT / 4; ++q) {
            int4 c = c4[q];
            int4 r = r4[q];
            int k = q * 4;
            myval[k + 0] = ((c.x & (BNODES - 1)) << 18) | r.x;  myb[k + 0] = c.x >> BSH;
            myval[k + 1] = ((c.y & (BNODES - 1)) << 18) | r.y;  myb[k + 1] = c.y >> BSH;
            myval[k + 2] = ((c.z & (BNODES - 1)) << 18) | r.z;  myb[k + 2] = c.z >> BSH;
            myval[k + 3] = ((c.w & (BNODES - 1)) << 18) | r.w;  myb[k + 3] = c.w >> BSH;
        }
#pragma unroll
        for (int k = 0; k < EPT; ++k) atomicAdd(&cnt[myb[k]], 1);
    } else {
#pragma unroll
        for (int k = 0; k < EPT; ++k) {
            int e = ebase + k;
            if (e < E) {
                int c = col[e];
                myval[k] = ((c & (BNODES - 1)) << 18) | row[e];
                myb[k] = c >> BSH;
                atomicAdd(&cnt[myb[k]], 1);
            } else {
                myb[k] = -1;
            }
        }
    }
    __syncthreads();

    int c = cnt[tid];
    int v = c;
    int lane = tid & 63, wid = tid >> 6;
#pragma unroll
    for (int off = 1; off < 64; off <<= 1) {
        int u = __shfl_up(v, off);
        if (lane >= off) v += u;
    }
    if (lane == 63) wtot[wid] = v;
    __syncthreads();
    if (tid == 0) {
        int running = 0;
#pragma unroll
        for (int i = 0; i < 8; ++i) { int w2 = wtot[i]; wtot[i] = running; running += w2; }
    }
    __syncthreads();
    int incl = v + wtot[wid];
    int excl = incl - c;
    pos[tid] = excl;
    cnt[tid] = excl;
    if (tid == 511) pos[512] = incl;
    if (tid < NBUCK) {
        lbase[tid] = tid * BCAP + (c ? atomicAdd(&gcur[tid], c) : 0);
    }
    __syncthreads();

#pragma unroll
    for (int k = 0; k < EPT; ++k) {
        if (myb[k] >= 0) {
            int p = atomicAdd(&cnt[myb[k]], 1);
            sortbuf[p] = myval[k];
        }
    }
    __syncthreads();

    for (int i = tid; i < tile_n; i += 512) {
        int lo = 0, hi = NBUCK - 1;
        while (lo < hi) {
            int mid = (lo + hi + 1) >> 1;
            if (pos[mid] <= i) lo = mid; else hi = mid - 1;
        }
        binned[lbase[lo] + (i - pos[lo])] = sortbuf[i];
    }
}

// ---------------------------------------------------------------------------
// passB2: per-bucket degree histogram -> deg[] (for bg1/bg2 scans) and
// h1b = bf16-pack(d * xacc), d = rsqrt(deg+1). One binned sweep.
__global__ __launch_bounds__(1024) void passB2_kernel(const int* __restrict__ gcur,
                                                      const int* __restrict__ binned,
                                                      const float* __restrict__ xacc,
                                                      int* __restrict__ deg,
                                                      uint4* __restrict__ h1b) {
    __shared__ int cnt[512];
    int b = blockIdx.x, tid = threadIdx.x;
    int bb = b * BCAP, be = bb + gcur[b];
    if (tid < 512) cnt[tid] = 0;
    __syncthreads();
    int e = bb + tid;
    for (; e + 3072 < be; e += 4096) {
        int p0 = binned[e], p1 = binned[e + 1024], p2 = binned[e + 2048], p3 = binned[e + 3072];
        atomicAdd(&cnt[p0 >> 18], 1); atomicAdd(&cnt[p1 >> 18], 1);
        atomicAdd(&cnt[p2 >> 18], 1); atomicAdd(&cnt[p3 >> 18], 1);
    }
    for (; e < be; e += 1024) atomicAdd(&cnt[binned[e] >> 18], 1);
    __syncthreads();
    if (tid < 512) {
        int n = (b << BSH) + tid;
        if (n < N_NODES) {
            int dv = cnt[tid];
            deg[n] = dv;
            float d = rsqrtf((float)dv + 1.0f);
            float a0 = xacc[0 * N_NODES + n], a1 = xacc[1 * N_NODES + n];
            float a2 = xacc[2 * N_NODES + n], a3 = xacc[3 * N_NODES + n];
            float a4 = xacc[4 * N_NODES + n], a5 = xacc[5 * N_NODES + n];
            uint4 o;
            o.x = pack2(d * a0, d * a1);
            o.y = pack2(d * a2, d * a3);
            o.z = pack2(d * a4, d * a5);
            o.w = __float_as_uint(d);
            h1b[n] = o;
        }
    }
}

// ---- shfl scan of deg over 512 nodes; INCL=0 leaves exclusive offsets in
// cnt (placement cursors), INCL=1 leaves inclusive ends (gather bounds). ----
#define DEG_SCAN(INCL)                                                          \
    {                                                                           \
        int n0 = (b << BSH) + tid;                                              \
        int v0 = (tid < 512 && n0 < N_NODES) ? deg[n0] : 0;                     \
        int v = v0;                                                             \
        int lane = tid & 63, wid = tid >> 6;                                    \
        _Pragma("unroll")                                                       \
        for (int off = 1; off < 64; off <<= 1) {                                \
            int u = __shfl_up(v, off);                                          \
            if (lane >= off) v += u;                                            \
        }                                                                       \
        if (wid < 8 && lane == 63) wtot[wid] = v;                               \
        __syncthreads();                                                        \
        if (tid == 0) {                                                         \
            int running = 0;                                                    \
            _Pragma("unroll")                                                   \
            for (int i = 0; i < 8; ++i) { int w2 = wtot[i]; wtot[i] = running; running += w2; } \
        }                                                                       \
        __syncthreads();                                                        \
        if (tid < 512) cnt[tid] = v + wtot[wid] - (INCL ? 0 : v0);              \
    }                                                                           \
    __syncthreads();

#define GATHER_BODY(TBL)                                                        \
    float a[H_HID] = {0.f, 0.f, 0.f, 0.f, 0.f, 0.f};                            \
    {                                                                           \
        int ee = s + sub;                                                       \
        for (; ee + 24 < e_end; ee += 32) {                                     \
            int i0 = stage[ee], i1 = stage[ee + 8];                             \
            int i2 = stage[ee + 16], i3 = stage[ee + 24];                       \
            uint4 v0 = TBL[i0], v1 = TBL[i1], v2 = TBL[i2], v3 = TBL[i3];       \
            a[0] += (bf_lo(v0.x) + bf_lo(v1.x)) + (bf_lo(v2.x) + bf_lo(v3.x));  \
            a[1] += (bf_hi(v0.x) + bf_hi(v1.x)) + (bf_hi(v2.x) + bf_hi(v3.x));  \
            a[2] += (bf_lo(v0.y) + bf_lo(v1.y)) + (bf_lo(v2.y) + bf_lo(v3.y));  \
            a[3] += (bf_hi(v0.y) + bf_hi(v1.y)) + (bf_hi(v2.y) + bf_hi(v3.y));  \
            a[4] += (bf_lo(v0.z) + bf_lo(v1.z)) + (bf_lo(v2.z) + bf_lo(v3.z));  \
            a[5] += (bf_hi(v0.z) + bf_hi(v1.z)) + (bf_hi(v2.z) + bf_hi(v3.z));  \
        }                                                                       \
        for (; ee < e_end; ee += 8) {                                           \
            uint4 vv = TBL[stage[ee]];                                          \
            a[0] += bf_lo(vv.x); a[1] += bf_hi(vv.x);                           \
            a[2] += bf_lo(vv.y); a[3] += bf_hi(vv.y);                           \
            a[4] += bf_lo(vv.z); a[5] += bf_hi(vv.z);                           \
        }                                                                       \
    }                                                                           \
    _Pragma("unroll")                                                           \
    for (int j = 0; j < H_HID; ++j) {                                           \
        _Pragma("unroll")                                                       \
        for (int off = 4; off > 0; off >>= 1) a[j] += __shfl_xor(a[j], off);    \
    }

// ---------------------------------------------------------------------------
// bg1: deg-scan (no count sweep) -> place (ONE binned sweep) -> publish sorted
// run to csr (int4, coalesced) -> layer-1 gather -> rs.
__global__ __launch_bounds__(1024) void bg1_kernel(const int* __restrict__ gcur,
                                                   const int* __restrict__ binned,
                                                   const int* __restrict__ deg,
                                                   const uint4* __restrict__ h1b,
                                                   const float* __restrict__ b1,
                                                   int* __restrict__ csr,
                                                   uint4* __restrict__ rs) {
    __shared__ int stage[BCAP];       // 68 KB
    __shared__ int cnt[512];
    __shared__ int wtot[8];
    int b = blockIdx.x, tid = threadIdx.x;
    int bb = b * BCAP, be = bb + gcur[b];
    int total = be - bb;

    DEG_SCAN(0)                        // cnt = exclusive offsets (cursors)

    // place: single binned sweep
    {
        int e = bb + tid;
        for (; e + 3072 < be; e += 4096) {
            int p0 = binned[e], p1 = binned[e + 1024];
            int p2 = binned[e + 2048], p3 = binned[e + 3072];
            int s0 = atomicAdd(&cnt[p0 >> 18], 1); stage[s0] = p0 & 0x3FFFF;
            int s1 = atomicAdd(&cnt[p1 >> 18], 1); stage[s1] = p1 & 0x3FFFF;
            int s2 = atomicAdd(&cnt[p2 >> 18], 1); stage[s2] = p2 & 0x3FFFF;
            int s3 = atomicAdd(&cnt[p3 >> 18], 1); stage[s3] = p3 & 0x3FFFF;
        }
        for (; e < be; e += 1024) {
            int p = binned[e];
            int s = atomicAdd(&cnt[p >> 18], 1); stage[s] = p & 0x3FFFF;
        }
    }
    __syncthreads();                   // stage complete; cnt = end offsets

    // publish sorted run (fire-and-forget coalesced stores; overlap gather)
    for (int i = tid * 4; i + 3 < total; i += 4096)
        *(int4*)(csr + bb + i) = *(const int4*)(stage + i);
    {
        int b4 = total & ~3, r = total - b4;
        if (tid < r) csr[bb + b4 + tid] = stage[b4 + tid];
    }

    // layer-1 gather -> rs
    int sub = tid & 7, grp = tid >> 3;
    for (int ch = 0; ch < 4; ++ch) {
        int ln = ch * 128 + grp;
        int n = (b << BSH) + ln;
        int s = ln ? cnt[ln - 1] : 0;
        int e_end = cnt[ln];
        GATHER_BODY(h1b)
        if (sub == 0 && n < N_NODES) {
            uint4 self = h1b[n];
            float d = __uint_as_float(self.w);
            float sf[H_HID] = {bf_lo(self.x), bf_hi(self.x), bf_lo(self.y),
                               bf_hi(self.y), bf_lo(self.z), bf_hi(self.z)};
            float r[H_HID];
#pragma unroll
            for (int j = 0; j < H_HID; ++j) {
                float vv = d * (a[j] + sf[j]) + b1[j];
                r[j] = d * (vv > 0.f ? vv : 0.f);    // pre-scaled for layer 2
            }
            uint4 o;
            o.x = pack2(r[0], r[1]);
            o.y = pack2(r[2], r[3]);
            o.z = pack2(r[4], r[5]);
            o.w = self.w;
            rs[n] = o;
        }
    }
}

// ---------------------------------------------------------------------------
// bg2: NO sort — deg-scan to run ends, int4-copy csr run into LDS, then
// layer-2 gather + W2 + hierarchical pool (round-4 verified body).
__global__ __launch_bounds__(1024) void bg2_kernel(const int* __restrict__ gcur,
                                                   const int* __restrict__ deg,
                                                   const int* __restrict__ csr,
                                                   const uint4* __restrict__ rs,
                                                   const float* __restrict__ W2,
                                                   const int* __restrict__ batch,
                                                   float* __restrict__ sums) {
    __shared__ int stage[BCAP];       // 68 KB
    __shared__ int cnt[512];
    __shared__ int wtot[8];
    __shared__ float w2s[H_HID * C_OUT];
    __shared__ float nv[128][C_OUT + 1];
    __shared__ int lg[128];
    __shared__ float gacc[2][C_OUT];
    __shared__ int sg0;
    int b = blockIdx.x, tid = threadIdx.x;
    int bb = b * BCAP;
    int total = gcur[b];
    if (tid < H_HID * C_OUT) w2s[tid] = W2[tid];
    if (tid < 2 * C_OUT) ((float*)gacc)[tid] = 0.f;
    if (tid == 0) sg0 = batch[b << BSH];

    // copy csr run -> LDS (issue global loads early)
    for (int i = tid * 4; i + 3 < total; i += 4096)
        *(int4*)(stage + i) = *(const int4*)(csr + bb + i);
    {
        int b4 = total & ~3, r = total - b4;
        if (tid < r) stage[b4 + tid] = csr[bb + b4 + tid];
    }

    DEG_SCAN(1)                        // cnt = inclusive run ends (also fences copy)

    int sub = tid & 7, grp = tid >> 3;
    for (int ch = 0; ch < 4; ++ch) {
        int ln = ch * 128 + grp;
        int n = (b << BSH) + ln;
        int s = ln ? cnt[ln - 1] : 0;
        int e_end = cnt[ln];
        GATHER_BODY(rs)
        uint4 self = {0u, 0u, 0u, 0u};
        if (n < N_NODES) self = rs[n];
        float d = (n < N_NODES) ? __uint_as_float(self.w) : 0.f;
        float t[H_HID] = {a[0] + bf_lo(self.x), a[1] + bf_hi(self.x),
                          a[2] + bf_lo(self.y), a[3] + bf_hi(self.y),
                          a[4] + bf_lo(self.z), a[5] + bf_hi(self.z)};
        {
            float accv = 0.f;
#pragma unroll
            for (int j = 0; j < H_HID; ++j) accv += t[j] * w2s[j * C_OUT + sub];
            nv[grp][sub] = d * accv;
            if (sub < 2) {
                float accv2 = 0.f;
#pragma unroll
                for (int j = 0; j < H_HID; ++j) accv2 += t[j] * w2s[j * C_OUT + sub + 8];
                nv[grp][sub + 8] = d * accv2;
            }
        }
        if (sub == 0) lg[grp] = (n < N_NODES) ? batch[n] : sg0;
        __syncthreads();
        if (tid < 80) {
            int seg = tid / C_OUT, cc = tid - seg * C_OUT;
            int g = -1; float av = 0.f;
            for (int i = 0; i < 16; ++i) {
                int wdx = seg * 16 + i;
                int gw = lg[wdx];
                if (gw != g) {
                    if (g >= 0) {
                        int r2 = g - sg0;
                        if (r2 < 2) atomicAdd(&gacc[r2][cc], av);
                        else atomicAdd(&sums[g * C_OUT + cc], av);
                    }
                    g = gw; av = 0.f;
                }
                av += nv[wdx][cc];
            }
            int r2 = g - sg0;
            if (r2 < 2) atomicAdd(&gacc[r2][cc], av);
            else atomicAdd(&sums[g * C_OUT + cc], av);
        }
        __syncthreads();
    }
    if (tid < 2 * C_OUT) {
        int r2 = tid / C_OUT, cc = tid - r2 * C_OUT;
        int g = sg0 + r2;
        if (g < G_BATCH) atomicAdd(&sums[g * C_OUT + cc], gacc[r2][cc]);
    }
}

// mean (counts via binary search on sorted batch) + b2 + log_softmax
__global__ void pool_finish_kernel(const float* __restrict__ sums, const int* __restrict__ batch,
                                   const float* __restrict__ b2, float* __restrict__ out) {
    int g = threadIdx.x;
    if (g >= G_BATCH) return;
    int lo = 0, hi = N_NODES;
    while (lo < hi) { int mid = (lo + hi) >> 1; if (batch[mid] < g) lo = mid + 1; else hi = mid; }
    int c0 = lo;
    hi = N_NODES;
    while (lo < hi) { int mid = (lo + hi) >> 1; if (batch[mid] < g + 1) lo = mid + 1; else hi = mid; }
    float inv = 1.0f / fmaxf((float)(lo - c0), 1.0f);
    float v[C_OUT], m = -INFINITY;
#pragma unroll
    for (int c = 0; c < C_OUT; ++c) {
        v[c] = sums[g * C_OUT + c] * inv + b2[c];
        m = fmaxf(m, v[c]);
    }
    float s = 0.f;
#pragma unroll
    for (int c = 0; c < C_OUT; ++c) s += expf(v[c] - m);
    float lse = m + logf(s);
#pragma unroll
    for (int c = 0; c < C_OUT; ++c) out[g * C_OUT + c] = v[c] - lse;
}

extern "C" void kernel_launch(void* const* d_in, const int* in_sizes, int n_in,
                              void* d_out, int out_size, void* d_ws, size_t ws_size,
                              hipStream_t stream) {
    const float* x   = (const float*)d_in[0];
    const int* ei    = (const int*)d_in[1];
    const int* row   = ei;
    const int* col   = ei + N_EDGES;
    const int* batch = (const int*)d_in[2];
    const float* W1  = (const float*)d_in[3];
    const float* b1  = (const float*)d_in[4];
    const float* W2  = (const float*)d_in[5];
    const float* b2  = (const float*)d_in[6];
    float* out = (float*)d_out;

    // workspace layout — region sizes multiples of 16 B so uint4 arrays stay aligned
    char* p = (char*)d_ws;
    float* sums   = (float*)p;  p += (size_t)G_BATCH * C_OUT * 4;       // [zero] 2560B
    int*   gcur   = (int*)p;    p += (size_t)400 * 4;                   // [zero] 1600B (391 used)
    int*   deg    = (int*)p;    p += (size_t)N_NODES * 4;               // 800KB
    int*   binned = (int*)p;    p += (size_t)NBUCK * BCAP * 4;          // 27.2MB (gapped)
    int*   csr    = (int*)p;    p += (size_t)NBUCK * BCAP * 4;          // 27.2MB (gapped)
    float* xacc   = (float*)p;  p += (size_t)H_HID * N_NODES * 4;       // 4.8MB SoA
    uint4* h1b    = (uint4*)p;  p += (size_t)N_NODES * 16;              // 3.2MB
    uint4* rs     = (uint4*)p;                                          // 3.2MB

    hipMemsetAsync(sums, 0, (size_t)G_BATCH * C_OUT * 4 + 400 * 4, stream);   // sums + gcur

    megaA_kernel  <<<NT + NXB, 512, 0, stream>>>(row, col, x, W1, gcur, binned, xacc, N_EDGES);
    passB2_kernel <<<NBUCK, 1024, 0, stream>>>(gcur, binned, xacc, deg, h1b);
    bg1_kernel    <<<NBUCK, 1024, 0, stream>>>(gcur, binned, deg, h1b, b1, csr, rs);
    bg2_kernel    <<<NBUCK, 1024, 0, stream>>>(gcur, deg, csr, rs, W2, batch, sums);
    pool_finish_kernel<<<1, 64, 0, stream>>>(sums, batch, b2, out);
}